// Round 1
// baseline (383.468 us; speedup 1.0000x reference)
//
#include <hip/hip_runtime.h>
#include <hip/hip_bf16.h>
#include <math.h>

// Problem constants
#define BB 2
#define CC 1024
#define HH 64
#define WW 64
#define HWH (HH*WW)          // 4096
#define TT (BB*HWH)          // 8192 tokens
#define EE 8
#define FFN 1024
// 256-row m-tiles: sum_e ceil(cnt_e/256) <= 16384/256 + (E-1) = 71
#define MAXTILES 71
#define HCAP (MAXTILES*256)  // 18176 padded rows

typedef __bf16 bf16x8 __attribute__((ext_vector_type(8)));
typedef __bf16 bf16x4 __attribute__((ext_vector_type(4)));
typedef float  f32x4  __attribute__((ext_vector_type(4)));

// async global->LDS, 16B per lane. LDS dest = wave-uniform base + lane*16.
__device__ __forceinline__ void gl_lds16(const __bf16* g, __bf16* l) {
    __builtin_amdgcn_global_load_lds(
        (const __attribute__((address_space(1))) void*)g,
        (__attribute__((address_space(3))) void*)l, 16, 0, 0);
}

__device__ __forceinline__ void barrier_raw() {
    asm volatile("" ::: "memory");
    __builtin_amdgcn_s_barrier();
    asm volatile("" ::: "memory");
}

#define WAITV(N) asm volatile("s_waitcnt vmcnt(" #N ")" ::: "memory")
#define LGKM0()  asm volatile("s_waitcnt lgkmcnt(0)" ::: "memory")

#define MFMA16(ACC, AF, BF)                                                   \
    _Pragma("unroll") for (int m_ = 0; m_ < 4; ++m_)                          \
    _Pragma("unroll") for (int n_ = 0; n_ < 4; ++n_)                          \
        ACC[m_][n_] = __builtin_amdgcn_mfma_f32_16x16x32_bf16(                \
            AF[m_], BF[n_], ACC[m_][n_], 0, 0, 0);

// ---------------------------------------------------------------------------
// k_prep: one launch doing (a) w1/w2/w3 fp32->bf16, (b) hs transpose -> X bf16,
// (c) router partial logits (16-way K-split).  All memory-bound, overlapped.
// grid: [0,12288) cvt | [12288,20480) xpose | [20480,20992) router partial
// ---------------------------------------------------------------------------
#define CVB 12288
#define XPB 8192
#define RTB 512
__global__ __launch_bounds__(256) void k_prep(
    const float* __restrict__ hs, const float* __restrict__ gate_w,
    const float* __restrict__ w1, const float* __restrict__ w2,
    const float* __restrict__ w3,
    __bf16* __restrict__ w1b, __bf16* __restrict__ w2b,
    __bf16* __restrict__ w3b, __bf16* __restrict__ X,
    float* __restrict__ logP) {
    __shared__ float sm[2112];   // union: xpose tile 32x33 | router gate 8x256
    const int bid = blockIdx.x;
    const int tid = threadIdx.x;

    if (bid < CVB) {
        // --- weight convert: 8 elems/thread ---
        const float* s; __bf16* d; int lb = bid;
        if (lb < 4096)      { s = w1; d = w1b; }
        else if (lb < 8192) { s = w2; d = w2b; lb -= 4096; }
        else                { s = w3; d = w3b; lb -= 8192; }
        const size_t i = (size_t)lb * 2048 + (size_t)tid * 8;
        const f32x4 v0 = *(const f32x4*)&s[i];
        const f32x4 v1 = *(const f32x4*)&s[i + 4];
        bf16x8 o;
#pragma unroll
        for (int j = 0; j < 4; ++j) { o[j] = (__bf16)v0[j]; o[4 + j] = (__bf16)v1[j]; }
        *(bf16x8*)&d[i] = o;
    } else if (bid < CVB + XPB) {
        // --- transpose hs (B,C,H,W) -> X [T,C] bf16 ---
        const int lb  = bid - CVB;
        const int hw0 = (lb & 127) * 32;
        const int c0  = ((lb >> 7) & 31) * 32;
        const int b   = lb >> 12;
        float (*tile)[33] = (float(*)[33])sm;
        const int tx = tid & 31, ty = tid >> 5;
        const float* src = hs + ((size_t)b * CC + c0) * HWH + hw0;
#pragma unroll
        for (int i = 0; i < 4; ++i)
            tile[ty + i * 8][tx] = src[(size_t)(ty + i * 8) * HWH + tx];
        __syncthreads();
        __bf16* dst = X + ((size_t)b * HWH + hw0) * CC + c0;
#pragma unroll
        for (int i = 0; i < 4; ++i) {
            const int hwl = ty + i * 8;
            dst[(size_t)hwl * CC + tx] = (__bf16)tile[tx][hwl];
        }
    } else {
        // --- router partial: block = (tokblk, quarter q); thread = (q2, token) ---
        const int lb  = bid - (CVB + XPB);
        const int q   = lb & 3;
        const int t64 = lb >> 2;
        float* g = sm;   // [8][256] slice of gate for channels [q*256, +256)
        for (int i = tid; i < 2048; i += 256)
            g[i] = gate_w[(size_t)(i >> 8) * CC + q * 256 + (i & 255)];
        __syncthreads();
        const int q2 = tid >> 6, tl = tid & 63;
        const int t  = t64 * 64 + tl;
        const int b  = t >> 12, hw = t & 4095;
        const float* xp = hs + (size_t)b * CC * HWH + hw;
        float l[EE];
#pragma unroll
        for (int e = 0; e < EE; ++e) l[e] = 0.0f;
        const int cbase = q * 256 + q2 * 64;
        for (int c2 = 0; c2 < 64; ++c2) {
            const float xv = xp[(size_t)(cbase + c2) * HWH];
#pragma unroll
            for (int e = 0; e < EE; ++e) l[e] += xv * g[e * 256 + q2 * 64 + c2];
        }
        float* dst = logP + ((size_t)(q * 4 + q2) * TT + t) * 8;
        f32x4 a, c;
#pragma unroll
        for (int e = 0; e < 4; ++e) { a[e] = l[e]; c[e] = l[4 + e]; }
        *(f32x4*)dst = a;
        *(f32x4*)&dst[4] = c;
    }
}

// ---------------------------------------------------------------------------
// k_top2: reduce 16 partials, top-2, renormalize, block-aggregated atomics.
// grid TT/256, block 256.
// ---------------------------------------------------------------------------
__global__ __launch_bounds__(256) void k_top2(const float* __restrict__ logP,
                                              int* __restrict__ cnt,
                                              int* __restrict__ idxl,
                                              int* __restrict__ tokE,
                                              int* __restrict__ tokP,
                                              float* __restrict__ tokW) {
    __shared__ int lcnt[EE], lbase[EE];
    const int tid = threadIdx.x;
    const int t   = blockIdx.x * 256 + tid;
    if (tid < EE) lcnt[tid] = 0;
    __syncthreads();

    float l[EE];
#pragma unroll
    for (int e = 0; e < EE; ++e) l[e] = 0.0f;
#pragma unroll
    for (int pq = 0; pq < 16; ++pq) {
        const float* src = logP + ((size_t)pq * TT + t) * 8;
        const f32x4 a = *(const f32x4*)src;
        const f32x4 c = *(const f32x4*)&src[4];
#pragma unroll
        for (int e = 0; e < 4; ++e) { l[e] += a[e]; l[4 + e] += c[e]; }
    }

    int e1 = 0; float v1 = l[0];
#pragma unroll
    for (int e = 1; e < EE; ++e) { if (l[e] > v1) { v1 = l[e]; e1 = e; } }
    int e2 = -1; float v2 = -1e30f;
#pragma unroll
    for (int e = 0; e < EE; ++e) { if (e != e1 && l[e] > v2) { v2 = l[e]; e2 = e; } }

    const float p2 = __expf(v2 - v1);
    const float rs = 1.0f / (1.0f + p2);

    const int m1 = atomicAdd(&lcnt[e1], 1);
    const int m2 = atomicAdd(&lcnt[e2], 1);
    __syncthreads();
    if (tid < EE) lbase[tid] = atomicAdd(&cnt[tid], lcnt[tid]);
    __syncthreads();
    const int p1pos = lbase[e1] + m1;
    const int p2pos = lbase[e2] + m2;

    idxl[e1 * TT + p1pos] = t;
    idxl[e2 * TT + p2pos] = t;
    tokE[t] = e1 | (e2 << 8);
    tokP[2 * t]     = p1pos;
    tokP[2 * t + 1] = p2pos;
    tokW[2 * t]     = rs;
    tokW[2 * t + 1] = p2 * rs;
}

// ---------------------------------------------------------------------------
// k_offsets: padded prefix offsets (256-granular) + dense (expert, m-tile) map.
// ---------------------------------------------------------------------------
__global__ void k_offsets(const int* __restrict__ cnt, int* __restrict__ off,
                          int* __restrict__ tileE, int* __restrict__ tileM,
                          int* __restrict__ nT) {
    if (threadIdx.x == 0) {
        int a = 0, n = 0;
        for (int e = 0; e < EE; ++e) {
            off[e] = a;
            const int mt = (cnt[e] + 255) >> 8;
            for (int m = 0; m < mt; ++m) { tileE[n] = e; tileM[n] = m * 256; ++n; }
            a += mt * 256;
        }
        nT[0] = n;
    }
}

// ---------------------------------------------------------------------------
// GEMM1: H = gelu(X@W1^T)*(X@W3^T), bf16, grouped.
// 8-phase-style schedule: BM=256, BN=128, BK=32, 512 thr (8 waves, 4Mx2N),
// per-wave 64x64 dual-acc. 4-slot LDS ring (128 KB), tile k+3 prefetched while
// computing k -> vmcnt(8) once per K-tile (never 0 in main loop). XOR-swizzled
// chunks (T2) staged via pre-swizzled global source. grid (FFN/128, MAXTILES).
// ---------------------------------------------------------------------------
__global__ __launch_bounds__(512, 2)
void k_gemm1(const __bf16* __restrict__ X, const __bf16* __restrict__ w1b,
             const __bf16* __restrict__ w3b, const int* __restrict__ cnt,
             const int* __restrict__ off, const int* __restrict__ idxl,
             const int* __restrict__ tileE, const int* __restrict__ tileM,
             const int* __restrict__ nT, __bf16* __restrict__ H) {
    if ((int)blockIdx.y >= nT[0]) return;
    const int e    = tileE[blockIdx.y];
    const int mt   = tileM[blockIdx.y];
    const int cntE = cnt[e];
    const int goff = off[e];
    const int n0   = blockIdx.x * 128;
    const __bf16* W1 = w1b + (size_t)e * FFN * CC;
    const __bf16* W3 = w3b + (size_t)e * FFN * CC;

    __shared__ __align__(16) __bf16 sA[4][256 * 32];    // 64 KB
    __shared__ __align__(16) __bf16 sB1[4][128 * 32];   // 32 KB
    __shared__ __align__(16) __bf16 sB3[4][128 * 32];   // 32 KB

    const int tid  = threadIdx.x;
    const int lane = tid & 63, wave = tid >> 6;
    const int l15  = lane & 15, lq = (lane >> 4) & 3;
    const int wm   = (wave >> 1) * 64;   // 4 m-waves
    const int wn   = (wave & 1) * 64;    // 2 n-waves
    // read-side swizzle: global chunk lq of row r lives in slot lq^(r&3)
    const int cs   = (lq ^ (l15 & 3)) * 8;
    // staging: thread covers row r_l, slot c4; fetch global chunk c4^(r_l&3)
    const int r_l  = tid >> 2;
    const int csw8 = ((tid & 3) ^ (r_l & 3)) * 8;

    int p0 = mt + r_l;        if (p0 > cntE - 1) p0 = cntE - 1;
    int p1 = mt + 128 + r_l;  if (p1 > cntE - 1) p1 = cntE - 1;
    const __bf16* gA0 = X + (size_t)idxl[e * TT + p0] * CC + csw8;
    const __bf16* gA1 = X + (size_t)idxl[e * TT + p1] * CC + csw8;
    const __bf16* gW1 = W1 + (size_t)(n0 + r_l) * CC + csw8;
    const __bf16* gW3 = W3 + (size_t)(n0 + r_l) * CC + csw8;

    const int aoff = (wm + l15) * 32 + cs;
    const int boff = (wn + l15) * 32 + cs;
    const int dA   = wave * 512;   // wave-uniform LDS element base

    f32x4 acc1[4][4] = {};
    f32x4 acc3[4][4] = {};

#define STG1A(S, KT) do { const int kb_ = (KT) * 32;                          \
        gl_lds16(gA0 + kb_, &sA[S][dA]);                                      \
        gl_lds16(gA1 + kb_, &sA[S][4096 + dA]); } while (0)
#define STG1B(S, KT) do { const int kb_ = (KT) * 32;                          \
        gl_lds16(gW1 + kb_, &sB1[S][dA]);                                     \
        gl_lds16(gW3 + kb_, &sB3[S][dA]); } while (0)

    // prologue: tiles 0,1,2 staged (12 loads/wave); tile0 landed, 8 in flight
    STG1A(0, 0); STG1B(0, 0);
    STG1A(1, 1); STG1B(1, 1);
    STG1A(2, 2); STG1B(2, 2);
    WAITV(8);
    barrier_raw();

#define TILE1(KT, S, PREF, WN) do {                                           \
    bf16x8 af_[4], bf_[4];                                                    \
    _Pragma("unroll") for (int i_ = 0; i_ < 4; ++i_) {                        \
        af_[i_] = *(const bf16x8*)&sA[S][aoff + i_ * 512];                    \
        bf_[i_] = *(const bf16x8*)&sB1[S][boff + i_ * 512];                   \
    }                                                                         \
    if (PREF) STG1A((S + 3) & 3, (KT) + 3);                                   \
    barrier_raw();                                                            \
    LGKM0();                                                                  \
    __builtin_amdgcn_s_setprio(1);                                            \
    MFMA16(acc1, af_, bf_);                                                   \
    __builtin_amdgcn_s_setprio(0);                                            \
    barrier_raw();                                                            \
    _Pragma("unroll") for (int i_ = 0; i_ < 4; ++i_)                          \
        bf_[i_] = *(const bf16x8*)&sB3[S][boff + i_ * 512];                   \
    if (PREF) STG1B((S + 3) & 3, (KT) + 3);                                   \
    barrier_raw();                                                            \
    LGKM0();                                                                  \
    __builtin_amdgcn_s_setprio(1);                                            \
    MFMA16(acc3, af_, bf_);                                                   \
    __builtin_amdgcn_s_setprio(0);                                            \
    WAITV(WN);                                                                \
    barrier_raw();                                                            \
} while (0)

    for (int k4 = 0; k4 < 28; k4 += 4) {
        TILE1(k4 + 0, 0, 1, 8);
        TILE1(k4 + 1, 1, 1, 8);
        TILE1(k4 + 2, 2, 1, 8);
        TILE1(k4 + 3, 3, 1, 8);
    }
    TILE1(28, 0, 1, 8);
    TILE1(29, 1, 0, 4);   // tile 30 must land; 31's 4 loads stay in flight
    TILE1(30, 2, 0, 0);   // tile 31 must land (tail only)
    TILE1(31, 3, 0, 63);  // no wait

    // epilogue: exact gelu * w3-branch -> packed H rows
#pragma unroll
    for (int m = 0; m < 4; ++m) {
        const int gb = goff + mt + wm + m * 16 + lq * 4;
#pragma unroll
        for (int n = 0; n < 4; ++n) {
            const int nb = n0 + wn + n * 16 + l15;
#pragma unroll
            for (int r = 0; r < 4; ++r) {
                const float a  = acc1[m][n][r];
                const float c  = acc3[m][n][r];
                const float ge = 0.5f * a * (1.0f + erff(a * 0.70710678118654752f));
                H[(size_t)(gb + r) * FFN + nb] = (__bf16)(ge * c);
            }
        }
    }
}

// ---------------------------------------------------------------------------
// GEMM2: Z = H @ W2^T, bf16, grouped. Same schedule: BM=256, BN=256, BK=32,
// 512 thr (8 waves, 2Mx4N), per-wave 128x64. 4-slot ring (128 KB), vmcnt(8).
// grid (CC/256, MAXTILES).
// ---------------------------------------------------------------------------
__global__ __launch_bounds__(512, 2)
void k_gemm2(const __bf16* __restrict__ H, const __bf16* __restrict__ w2b,
             const int* __restrict__ off, const int* __restrict__ tileE,
             const int* __restrict__ tileM, const int* __restrict__ nT,
             __bf16* __restrict__ Z) {
    if ((int)blockIdx.y >= nT[0]) return;
    const int e    = tileE[blockIdx.y];
    const int mt   = tileM[blockIdx.y];
    const int goff = off[e];
    const int n0   = blockIdx.x * 256;
    const __bf16* W2 = w2b + (size_t)e * CC * FFN;
    const __bf16* Ar = H + (size_t)(goff + mt) * FFN;

    __shared__ __align__(16) __bf16 sA[4][256 * 32];   // 64 KB
    __shared__ __align__(16) __bf16 sB[4][256 * 32];   // 64 KB

    const int tid  = threadIdx.x;
    const int lane = tid & 63, wave = tid >> 6;
    const int l15  = lane & 15, lq = (lane >> 4) & 3;
    const int wm   = (wave & 1) * 128;   // 2 m-waves
    const int wn   = (wave >> 1) * 64;   // 4 n-waves
    const int cs   = (lq ^ (l15 & 3)) * 8;
    const int r_l  = tid >> 2;
    const int csw8 = ((tid & 3) ^ (r_l & 3)) * 8;

    const __bf16* gA0 = Ar + (size_t)r_l * FFN + csw8;
    const __bf16* gA1 = Ar + (size_t)(128 + r_l) * FFN + csw8;
    const __bf16* gB0 = W2 + (size_t)(n0 + r_l) * FFN + csw8;
    const __bf16* gB1 = W2 + (size_t)(n0 + 128 + r_l) * FFN + csw8;

    const int aoff = (wm + l15) * 32 + cs;
    const int boff = (wn + l15) * 32 + cs;
    const int dA   = wave * 512;

    f32x4 accL[4][4] = {};   // m-frags 0..3
    f32x4 accH[4][4] = {};   // m-frags 4..7

#define STG2A(S, KT) do { const int kb_ = (KT) * 32;                          \
        gl_lds16(gA0 + kb_, &sA[S][dA]);                                      \
        gl_lds16(gA1 + kb_, &sA[S][4096 + dA]); } while (0)
#define STG2B(S, KT) do { const int kb_ = (KT) * 32;                          \
        gl_lds16(gB0 + kb_, &sB[S][dA]);                                      \
        gl_lds16(gB1 + kb_, &sB[S][4096 + dA]); } while (0)

    STG2A(0, 0); STG2B(0, 0);
    STG2A(1, 1); STG2B(1, 1);
    STG2A(2, 2); STG2B(2, 2);
    WAITV(8);
    barrier_raw();

#define TILE2(KT, S, PREF, WN) do {                                           \
    bf16x8 af_[4], bf_[4];                                                    \
    _Pragma("unroll") for (int i_ = 0; i_ < 4; ++i_) {                        \
        af_[i_] = *(const bf16x8*)&sA[S][aoff + i_ * 512];                    \
        bf_[i_] = *(const bf16x8*)&sB[S][boff + i_ * 512];                    \
    }                                                                         \
    if (PREF) STG2A((S + 3) & 3, (KT) + 3);                                   \
    barrier_raw();                                                            \
    LGKM0();                                                                  \
    __builtin_amdgcn_s_setprio(1);                                            \
    MFMA16(accL, af_, bf_);                                                   \
    __builtin_amdgcn_s_setprio(0);                                            \
    barrier_raw();                                                            \
    _Pragma("unroll") for (int i_ = 0; i_ < 4; ++i_)                          \
        af_[i_] = *(const bf16x8*)&sA[S][aoff + 2048 + i_ * 512];             \
    if (PREF) STG2B((S + 3) & 3, (KT) + 3);                                   \
    barrier_raw();                                                            \
    LGKM0();                                                                  \
    __builtin_amdgcn_s_setprio(1);                                            \
    MFMA16(accH, af_, bf_);                                                   \
    __builtin_amdgcn_s_setprio(0);                                            \
    WAITV(WN);                                                                \
    barrier_raw();                                                            \
} while (0)

    for (int k4 = 0; k4 < 28; k4 += 4) {
        TILE2(k4 + 0, 0, 1, 8);
        TILE2(k4 + 1, 1, 1, 8);
        TILE2(k4 + 2, 2, 1, 8);
        TILE2(k4 + 3, 3, 1, 8);
    }
    TILE2(28, 0, 1, 8);
    TILE2(29, 1, 0, 4);
    TILE2(30, 2, 0, 0);
    TILE2(31, 3, 0, 63);

#pragma unroll
    for (int m = 0; m < 4; ++m) {
#pragma unroll
        for (int n = 0; n < 4; ++n) {
            const int nb = n0 + wn + n * 16 + l15;
#pragma unroll
            for (int r = 0; r < 4; ++r) {
                Z[(size_t)(goff + mt + wm + m * 16 + lq * 4 + r) * CC + nb] =
                    (__bf16)accL[m][n][r];
                Z[(size_t)(goff + mt + wm + 64 + m * 16 + lq * 4 + r) * CC + nb] =
                    (__bf16)accH[m][n][r];
            }
        }
    }
}

// ---------------------------------------------------------------------------
// k_combine: out[t,c] = w1*Z[r1,c] + w2*Z[r2,c], transposed to (B,C,H,W).
// ---------------------------------------------------------------------------
__global__ __launch_bounds__(256) void k_combine(const __bf16* __restrict__ Z,
                                                 const int* __restrict__ off,
                                                 const int* __restrict__ tokE,
                                                 const int* __restrict__ tokP,
                                                 const float* __restrict__ tokW,
                                                 float* __restrict__ out) {
    __shared__ float tile[32][33];
    const int t0 = blockIdx.x * 32;
    const int c0 = blockIdx.y * 32;
    const int tx = threadIdx.x & 31;
    const int ty = threadIdx.x >> 5;

#pragma unroll
    for (int i = 0; i < 4; ++i) {
        const int tl = ty + 8 * i;
        const int t  = t0 + tl;
        const int ee = tokE[t];
        const int e1 = ee & 0xff, e2 = ee >> 8;
        const int r1 = off[e1] + tokP[2 * t];
        const int r2 = off[e2] + tokP[2 * t + 1];
        const float v = tokW[2 * t]     * (float)Z[(size_t)r1 * CC + c0 + tx]
                      + tokW[2 * t + 1] * (float)Z[(size_t)r2 * CC + c0 + tx];
        tile[tl][tx] = v;
    }
    __syncthreads();

    const int b   = t0 >> 12;
    const int hw0 = t0 & 4095;
#pragma unroll
    for (int i = 0; i < 4; ++i) {
        const int cl = ty + 8 * i;
        out[(size_t)b * CC * HWH + (size_t)(c0 + cl) * HWH + hw0 + tx] = tile[tx][cl];
    }
}

// ---------------------------------------------------------------------------
extern "C" void kernel_launch(void* const* d_in, const int* in_sizes, int n_in,
                              void* d_out, int out_size, void* d_ws, size_t ws_size,
                              hipStream_t stream) {
    const float* hs     = (const float*)d_in[0];
    const float* gate_w = (const float*)d_in[1];
    const float* w1     = (const float*)d_in[2];
    const float* w2     = (const float*)d_in[3];
    const float* w3     = (const float*)d_in[4];
    float* out = (float*)d_out;

    // ws layout (~100 MiB). logP overlays Hbuf (dead until gemm1);
    // Zbuf overlays w1b/w3b/X-head (dead after gemm1).
    const size_t WSZ = (size_t)EE * FFN * CC * 2;   // 16 MB per bf16 weight
    char* ws = (char*)d_ws;
    __bf16* w2b  = (__bf16*)ws;                     // [0, 16M)   live: gemm2
    __bf16* w1b  = (__bf16*)(ws + WSZ);             // [16M,32M)  live: gemm1
    __bf16* w3b  = (__bf16*)(ws + 2 * WSZ);         // [32M,48M)  live: gemm1
    __bf16* X    = (__bf16*)(ws + 3 * WSZ);         // [48M,64M)  live: gemm1
    __bf16* Zbuf = (__bf16*)(ws + WSZ);             // overlays w1b,w3b,X-head
    __bf16* Hbuf = (__bf16*)(ws + 4 * WSZ);         // ~35.5 MiB
    float*  logP = (float*)Hbuf;                    // 4 MB, dead before gemm1
    char* p = ws + 4 * WSZ + (size_t)HCAP * FFN * 2;
    int*   idxl  = (int*)p;           p += (size_t)EE * TT * 4;
    int*   tokE  = (int*)p;           p += (size_t)TT * 4;
    int*   tokP  = (int*)p;           p += (size_t)2 * TT * 4;
    float* tokW  = (float*)p;         p += (size_t)2 * TT * 4;
    int*   cnt   = (int*)p;           p += 256;
    int*   off   = (int*)p;           p += 256;
    int*   tileE = (int*)p;           p += MAXTILES * 4;
    int*   tileM = (int*)p;           p += MAXTILES * 4;
    int*   nT    = (int*)p;

    hipMemsetAsync(cnt, 0, EE * sizeof(int), stream);

    k_prep<<<CVB + XPB + RTB, 256, 0, stream>>>(
        hs, gate_w, w1, w2, w3, w1b, w2b, w3b, X, logP);
    k_top2<<<TT / 256, 256, 0, stream>>>(logP, cnt, idxl, tokE, tokP, tokW);
    k_offsets<<<1, 64, 0, stream>>>(cnt, off, tileE, tileM, nT);

    k_gemm1<<<dim3(FFN / 128, MAXTILES), 512, 0, stream>>>(
        X, w1b, w3b, cnt, off, idxl, tileE, tileM, nT, Hbuf);
    k_gemm2<<<dim3(CC / 256, MAXTILES), 512, 0, stream>>>(
        Hbuf, w2b, off, tileE, tileM, nT, Zbuf);
    k_combine<<<dim3(TT / 32, CC / 32), 256, 0, stream>>>(
        Zbuf, off, tokE, tokP, tokW, out);
}

// Round 2
// 380.854 us; speedup vs baseline: 1.0069x; 1.0069x over previous
//
#include <hip/hip_runtime.h>
#include <hip/hip_bf16.h>
#include <math.h>

// Problem constants
#define BB 2
#define CC 1024
#define HH 64
#define WW 64
#define HWH (HH*WW)          // 4096
#define TT (BB*HWH)          // 8192 tokens
#define EE 8
#define FFN 1024
// 256-row m-tiles: sum_e ceil(cnt_e/256) <= 16384/256 + (E-1) = 71
#define MAXTILES 71
#define HCAP (MAXTILES*256)  // 18176 padded rows

typedef __bf16 bf16x8 __attribute__((ext_vector_type(8)));
typedef float  f32x4  __attribute__((ext_vector_type(4)));

// async global->LDS, 16B per lane. LDS dest = wave-uniform base + lane*16.
__device__ __forceinline__ void gl_lds16(const __bf16* g, __bf16* l) {
    __builtin_amdgcn_global_load_lds(
        (const __attribute__((address_space(1))) void*)g,
        (__attribute__((address_space(3))) void*)l, 16, 0, 0);
}

__device__ __forceinline__ void barrier_raw() {
    asm volatile("" ::: "memory");
    __builtin_amdgcn_s_barrier();
    asm volatile("" ::: "memory");
}

#define WAITV(N) asm volatile("s_waitcnt vmcnt(" #N ")" ::: "memory")
#define LGKM0()  asm volatile("s_waitcnt lgkmcnt(0)" ::: "memory")
#define SCHED0() __builtin_amdgcn_sched_barrier(0)
#define PRIO1()  __builtin_amdgcn_s_setprio(1)
#define PRIO0()  __builtin_amdgcn_s_setprio(0)

// ---------------------------------------------------------------------------
// k_prep: one launch doing (a) w1/w2/w3 fp32->bf16, (b) hs transpose -> X bf16,
// (c) router partial logits (16-way K-split).  All memory-bound, overlapped.
// ---------------------------------------------------------------------------
#define CVB 12288
#define XPB 8192
#define RTB 512
__global__ __launch_bounds__(256) void k_prep(
    const float* __restrict__ hs, const float* __restrict__ gate_w,
    const float* __restrict__ w1, const float* __restrict__ w2,
    const float* __restrict__ w3,
    __bf16* __restrict__ w1b, __bf16* __restrict__ w2b,
    __bf16* __restrict__ w3b, __bf16* __restrict__ X,
    float* __restrict__ logP) {
    __shared__ float sm[2112];   // union: xpose tile 32x33 | router gate 8x256
    const int bid = blockIdx.x;
    const int tid = threadIdx.x;

    if (bid < CVB) {
        // --- weight convert: 8 elems/thread ---
        const float* s; __bf16* d; int lb = bid;
        if (lb < 4096)      { s = w1; d = w1b; }
        else if (lb < 8192) { s = w2; d = w2b; lb -= 4096; }
        else                { s = w3; d = w3b; lb -= 8192; }
        const size_t i = (size_t)lb * 2048 + (size_t)tid * 8;
        const f32x4 v0 = *(const f32x4*)&s[i];
        const f32x4 v1 = *(const f32x4*)&s[i + 4];
        bf16x8 o;
#pragma unroll
        for (int j = 0; j < 4; ++j) { o[j] = (__bf16)v0[j]; o[4 + j] = (__bf16)v1[j]; }
        *(bf16x8*)&d[i] = o;
    } else if (bid < CVB + XPB) {
        // --- transpose hs (B,C,H,W) -> X [T,C] bf16 ---
        const int lb  = bid - CVB;
        const int hw0 = (lb & 127) * 32;
        const int c0  = ((lb >> 7) & 31) * 32;
        const int b   = lb >> 12;
        float (*tile)[33] = (float(*)[33])sm;
        const int tx = tid & 31, ty = tid >> 5;
        const float* src = hs + ((size_t)b * CC + c0) * HWH + hw0;
#pragma unroll
        for (int i = 0; i < 4; ++i)
            tile[ty + i * 8][tx] = src[(size_t)(ty + i * 8) * HWH + tx];
        __syncthreads();
        __bf16* dst = X + ((size_t)b * HWH + hw0) * CC + c0;
#pragma unroll
        for (int i = 0; i < 4; ++i) {
            const int hwl = ty + i * 8;
            dst[(size_t)hwl * CC + tx] = (__bf16)tile[tx][hwl];
        }
    } else {
        // --- router partial: block = (tokblk, quarter q); thread = (q2, token) ---
        const int lb  = bid - (CVB + XPB);
        const int q   = lb & 3;
        const int t64 = lb >> 2;
        float* g = sm;   // [8][256] slice of gate for channels [q*256, +256)
        for (int i = tid; i < 2048; i += 256)
            g[i] = gate_w[(size_t)(i >> 8) * CC + q * 256 + (i & 255)];
        __syncthreads();
        const int q2 = tid >> 6, tl = tid & 63;
        const int t  = t64 * 64 + tl;
        const int b  = t >> 12, hw = t & 4095;
        const float* xp = hs + (size_t)b * CC * HWH + hw;
        float l[EE];
#pragma unroll
        for (int e = 0; e < EE; ++e) l[e] = 0.0f;
        const int cbase = q * 256 + q2 * 64;
        for (int c2 = 0; c2 < 64; ++c2) {
            const float xv = xp[(size_t)(cbase + c2) * HWH];
#pragma unroll
            for (int e = 0; e < EE; ++e) l[e] += xv * g[e * 256 + q2 * 64 + c2];
        }
        float* dst = logP + ((size_t)(q * 4 + q2) * TT + t) * 8;
        f32x4 a, c;
#pragma unroll
        for (int e = 0; e < 4; ++e) { a[e] = l[e]; c[e] = l[4 + e]; }
        *(f32x4*)dst = a;
        *(f32x4*)&dst[4] = c;
    }
}

// ---------------------------------------------------------------------------
// k_top2: reduce 16 partials, top-2, renormalize, block-aggregated atomics.
// ---------------------------------------------------------------------------
__global__ __launch_bounds__(256) void k_top2(const float* __restrict__ logP,
                                              int* __restrict__ cnt,
                                              int* __restrict__ idxl,
                                              int* __restrict__ tokE,
                                              int* __restrict__ tokP,
                                              float* __restrict__ tokW) {
    __shared__ int lcnt[EE], lbase[EE];
    const int tid = threadIdx.x;
    const int t   = blockIdx.x * 256 + tid;
    if (tid < EE) lcnt[tid] = 0;
    __syncthreads();

    float l[EE];
#pragma unroll
    for (int e = 0; e < EE; ++e) l[e] = 0.0f;
#pragma unroll
    for (int pq = 0; pq < 16; ++pq) {
        const float* src = logP + ((size_t)pq * TT + t) * 8;
        const f32x4 a = *(const f32x4*)src;
        const f32x4 c = *(const f32x4*)&src[4];
#pragma unroll
        for (int e = 0; e < 4; ++e) { l[e] += a[e]; l[4 + e] += c[e]; }
    }

    int e1 = 0; float v1 = l[0];
#pragma unroll
    for (int e = 1; e < EE; ++e) { if (l[e] > v1) { v1 = l[e]; e1 = e; } }
    int e2 = -1; float v2 = -1e30f;
#pragma unroll
    for (int e = 0; e < EE; ++e) { if (e != e1 && l[e] > v2) { v2 = l[e]; e2 = e; } }

    const float p2 = __expf(v2 - v1);
    const float rs = 1.0f / (1.0f + p2);

    const int m1 = atomicAdd(&lcnt[e1], 1);
    const int m2 = atomicAdd(&lcnt[e2], 1);
    __syncthreads();
    if (tid < EE) lbase[tid] = atomicAdd(&cnt[tid], lcnt[tid]);
    __syncthreads();
    const int p1pos = lbase[e1] + m1;
    const int p2pos = lbase[e2] + m2;

    idxl[e1 * TT + p1pos] = t;
    idxl[e2 * TT + p2pos] = t;
    tokE[t] = e1 | (e2 << 8);
    tokP[2 * t]     = p1pos;
    tokP[2 * t + 1] = p2pos;
    tokW[2 * t]     = rs;
    tokW[2 * t + 1] = p2 * rs;
}

// ---------------------------------------------------------------------------
// k_offsets: padded prefix offsets (256-granular) + dense (expert, m-tile) map.
// ---------------------------------------------------------------------------
__global__ void k_offsets(const int* __restrict__ cnt, int* __restrict__ off,
                          int* __restrict__ tileE, int* __restrict__ tileM,
                          int* __restrict__ nT) {
    if (threadIdx.x == 0) {
        int a = 0, n = 0;
        for (int e = 0; e < EE; ++e) {
            off[e] = a;
            const int mt = (cnt[e] + 255) >> 8;
            for (int m = 0; m < mt; ++m) { tileE[n] = e; tileM[n] = m * 256; ++n; }
            a += mt * 256;
        }
        nT[0] = n;
    }
}

// ---------------------------------------------------------------------------
// GEMM1: H = gelu(X@W1^T)*(X@W3^T), bf16, grouped. m201-geometry port:
// BM=256, BK=64, 512thr/8 waves (2M x 4N-quarters), per-wave 128x64 output
// (acc[8][4]). B-tile = 128 W1-rows + 128 W3-rows interleaved at 32-col
// granularity so each wave holds both operands of the same H-columns.
// LDS: 2 slots x (A,B) x 2 K-halves x 256rows x 32K = 128 KiB. Row stride
// 64B -> R0's proven zero-conflict XOR swizzle (slot = lq ^ ((l15>>1)&3)).
// 4 phases/K-tile, counted vmcnt(4) at phases 2 & 4. grid (FFN/128, MAXTILES).
// ---------------------------------------------------------------------------
__global__ __launch_bounds__(512, 1)
void k_gemm1(const __bf16* __restrict__ X, const __bf16* __restrict__ w1b,
             const __bf16* __restrict__ w3b, const int* __restrict__ cnt,
             const int* __restrict__ off, const int* __restrict__ idxl,
             const int* __restrict__ tileE, const int* __restrict__ tileM,
             const int* __restrict__ nT, __bf16* __restrict__ H) {
    if ((int)blockIdx.y >= nT[0]) return;
    const int e    = tileE[blockIdx.y];
    const int mt   = tileM[blockIdx.y];
    const int cntE = cnt[e];
    const int goff = off[e];
    const int n0   = blockIdx.x * 128;   // H-column base
    const __bf16* W1 = w1b + (size_t)e * FFN * CC;
    const __bf16* W3 = w3b + (size_t)e * FFN * CC;

    __shared__ __align__(16) __bf16 sA[2][2][256 * 32];   // [slot][khalf] 64 KB
    __shared__ __align__(16) __bf16 sB[2][2][256 * 32];   // 64 KB

    const int tid  = threadIdx.x;
    const int lane = tid & 63, wave = tid >> 6;
    const int l15  = lane & 15, lq = lane >> 4;
    const int wm   = wave & 1;     // m-half (rows wm*128..)
    const int q    = wave >> 1;    // n-quarter
    const int rsw  = (lq ^ ((l15 >> 1) & 3)) * 8;       // frag-read swizzled chunk

    // staging mapping: lane -> row (lane>>2), chunk-slot (lane&3)
    const int rl  = lane >> 2;
    const int csw = ((lane & 3) ^ ((rl >> 1) & 3)) * 8;  // pre-swizzled global chunk

    // A: gathered token rows mt + wave*32 + {0,16} + rl (clamped to cntE-1)
    int pr0 = mt + wave * 32 + rl;       if (pr0 > cntE - 1) pr0 = cntE - 1;
    int pr1 = mt + wave * 32 + 16 + rl;  if (pr1 > cntE - 1) pr1 = cntE - 1;
    const __bf16* gA0 = X + (size_t)idxl[e * TT + pr0] * CC + csw;
    const __bf16* gA1 = X + (size_t)idxl[e * TT + pr1] * CC + csw;
    // B: wave even -> W1, wave odd -> W3; cols n0 + (wave>>1)*32 + {0,16} + rl
    const __bf16* WB = (wave & 1) ? W3 : W1;
    const __bf16* gB0 = WB + (size_t)(n0 + q * 32 + rl) * CC + csw;
    const __bf16* gB1 = WB + (size_t)(n0 + q * 32 + 16 + rl) * CC + csw;

    const int st0  = wave * 1024;                 // stage LDS base (elems)
    const int aoff = (wm * 128 + l15) * 32 + rsw; // + mf*512
    const int boff = (q * 64 + l15) * 32 + rsw;   // + nf*512

    f32x4 acc[8][4] = {};

#define G1_STGA(S, KS, KB) do {                                               \
    gl_lds16(gA0 + (KB) + (KS) * 32, &sA[S][KS][st0]);                        \
    gl_lds16(gA1 + (KB) + (KS) * 32, &sA[S][KS][st0 + 512]); } while (0)
#define G1_STGB(S, KS, KB) do {                                               \
    gl_lds16(gB0 + (KB) + (KS) * 32, &sB[S][KS][st0]);                        \
    gl_lds16(gB1 + (KB) + (KS) * 32, &sB[S][KS][st0 + 512]); } while (0)
#define G1_LDA(DST, S, KS, MF0)                                               \
    _Pragma("unroll") for (int mf_ = 0; mf_ < 4; ++mf_)                       \
        DST[mf_] = *(const bf16x8*)&sA[S][KS][aoff + (MF0 + mf_) * 512];
#define G1_LDB(DST, S, KS)                                                    \
    _Pragma("unroll") for (int nf_ = 0; nf_ < 4; ++nf_)                       \
        DST[nf_] = *(const bf16x8*)&sB[S][KS][boff + nf_ * 512];
#define G1_MM(M0, AF, BF)                                                     \
    _Pragma("unroll") for (int m_ = 0; m_ < 4; ++m_)                          \
    _Pragma("unroll") for (int n_ = 0; n_ < 4; ++n_)                          \
        acc[M0 + m_][n_] = __builtin_amdgcn_mfma_f32_16x16x32_bf16(           \
            AF[m_], BF[n_], acc[M0 + m_][n_], 0, 0, 0);

#define G1_TILE(S, KB, STG, LAST) do {                                        \
    bf16x8 af[4], bv[4];                                                      \
    /* phase 1: ks0, m-frags 0-3 (+ all B ks0) */                             \
    G1_LDA(af, S, 0, 0); G1_LDB(bv, S, 0);                                    \
    if (STG) G1_STGA((S) ^ 1, 0, KB);                                         \
    barrier_raw(); LGKM0(); SCHED0();                                         \
    PRIO1(); G1_MM(0, af, bv); PRIO0(); barrier_raw();                        \
    /* phase 2: ks0, m-frags 4-7 */                                           \
    G1_LDA(af, S, 0, 4);                                                      \
    if (STG) G1_STGB((S) ^ 1, 0, KB);                                         \
    if (LAST) { WAITV(0); } else { WAITV(4); }                                \
    barrier_raw(); LGKM0(); SCHED0();                                         \
    PRIO1(); G1_MM(4, af, bv); PRIO0(); barrier_raw();                        \
    /* phase 3: ks1, m-frags 0-3 (+ all B ks1) */                             \
    G1_LDA(af, S, 1, 0); G1_LDB(bv, S, 1);                                    \
    if (STG) G1_STGA((S) ^ 1, 1, KB);                                         \
    barrier_raw(); LGKM0(); SCHED0();                                         \
    PRIO1(); G1_MM(0, af, bv); PRIO0(); barrier_raw();                        \
    /* phase 4: ks1, m-frags 4-7 */                                           \
    G1_LDA(af, S, 1, 4);                                                      \
    if (STG) G1_STGB((S) ^ 1, 1, KB);                                         \
    if (!LAST) { WAITV(4); }                                                  \
    barrier_raw(); LGKM0(); SCHED0();                                         \
    PRIO1(); G1_MM(4, af, bv); PRIO0(); barrier_raw();                        \
} while (0)

    // prologue: tile0 -> slot0, full drain once
    G1_STGA(0, 0, 0); G1_STGB(0, 0, 0); G1_STGA(0, 1, 0); G1_STGB(0, 1, 0);
    WAITV(0);
    barrier_raw();

    int kb = 64;   // element offset of tile being prefetched
    for (int it = 0; it < 7; ++it) {
        G1_TILE(0, kb, 1, 0); kb += 64;
        G1_TILE(1, kb, 1, 0); kb += 64;
    }
    G1_TILE(0, kb, 1, 0);   // tile 14, stages tile 15 (kb=960)
    G1_TILE(1, 0, 0, 1);    // tile 15, no stage, final drain at phase 2

#undef G1_STGA
#undef G1_STGB
#undef G1_LDA
#undef G1_LDB
#undef G1_MM
#undef G1_TILE

    // epilogue: acc[mf][jp] (W1) pairs with acc[mf][jp+2] (W3), same H-col
#pragma unroll
    for (int mf = 0; mf < 8; ++mf) {
        const int gr = goff + mt + wm * 128 + mf * 16 + lq * 4;
#pragma unroll
        for (int jp = 0; jp < 2; ++jp) {
            const int col = n0 + q * 32 + jp * 16 + l15;
#pragma unroll
            for (int r = 0; r < 4; ++r) {
                const float a  = acc[mf][jp][r];
                const float c  = acc[mf][jp + 2][r];
                const float ge = 0.5f * a * (1.0f + erff(a * 0.70710678118654752f));
                H[(size_t)(gr + r) * FFN + col] = (__bf16)(ge * c);
            }
        }
    }
}

// ---------------------------------------------------------------------------
// GEMM2: Z = H @ W2^T, bf16, grouped. Same m201 geometry: BM=256, BN=256,
// BK=64, per-wave 128x64.  grid (CC/256, MAXTILES).
// ---------------------------------------------------------------------------
__global__ __launch_bounds__(512, 1)
void k_gemm2(const __bf16* __restrict__ H, const __bf16* __restrict__ w2b,
             const int* __restrict__ off, const int* __restrict__ tileE,
             const int* __restrict__ tileM, const int* __restrict__ nT,
             __bf16* __restrict__ Z) {
    if ((int)blockIdx.y >= nT[0]) return;
    const int e    = tileE[blockIdx.y];
    const int mt   = tileM[blockIdx.y];
    const int goff = off[e];
    const int n0   = blockIdx.x * 256;
    const __bf16* W2 = w2b + (size_t)e * CC * FFN;
    const __bf16* Ar = H + (size_t)(goff + mt) * FFN;

    __shared__ __align__(16) __bf16 sA[2][2][256 * 32];
    __shared__ __align__(16) __bf16 sB[2][2][256 * 32];

    const int tid  = threadIdx.x;
    const int lane = tid & 63, wave = tid >> 6;
    const int l15  = lane & 15, lq = lane >> 4;
    const int wm   = wave & 1;
    const int q    = wave >> 1;
    const int rsw  = (lq ^ ((l15 >> 1) & 3)) * 8;
    const int rl   = lane >> 2;
    const int csw  = ((lane & 3) ^ ((rl >> 1) & 3)) * 8;

    const __bf16* gA0 = Ar + (size_t)(wave * 32 + rl) * FFN + csw;
    const __bf16* gA1 = Ar + (size_t)(wave * 32 + 16 + rl) * FFN + csw;
    const __bf16* gB0 = W2 + (size_t)(n0 + wave * 32 + rl) * FFN + csw;
    const __bf16* gB1 = W2 + (size_t)(n0 + wave * 32 + 16 + rl) * FFN + csw;

    const int st0  = wave * 1024;
    const int aoff = (wm * 128 + l15) * 32 + rsw;
    const int boff = (q * 64 + l15) * 32 + rsw;

    f32x4 acc[8][4] = {};

#define G2_STGA(S, KS, KB) do {                                               \
    gl_lds16(gA0 + (KB) + (KS) * 32, &sA[S][KS][st0]);                        \
    gl_lds16(gA1 + (KB) + (KS) * 32, &sA[S][KS][st0 + 512]); } while (0)
#define G2_STGB(S, KS, KB) do {                                               \
    gl_lds16(gB0 + (KB) + (KS) * 32, &sB[S][KS][st0]);                        \
    gl_lds16(gB1 + (KB) + (KS) * 32, &sB[S][KS][st0 + 512]); } while (0)
#define G2_LDA(DST, S, KS, MF0)                                               \
    _Pragma("unroll") for (int mf_ = 0; mf_ < 4; ++mf_)                       \
        DST[mf_] = *(const bf16x8*)&sA[S][KS][aoff + (MF0 + mf_) * 512];
#define G2_LDB(DST, S, KS)                                                    \
    _Pragma("unroll") for (int nf_ = 0; nf_ < 4; ++nf_)                       \
        DST[nf_] = *(const bf16x8*)&sB[S][KS][boff + nf_ * 512];
#define G2_MM(M0, AF, BF)                                                     \
    _Pragma("unroll") for (int m_ = 0; m_ < 4; ++m_)                          \
    _Pragma("unroll") for (int n_ = 0; n_ < 4; ++n_)                          \
        acc[M0 + m_][n_] = __builtin_amdgcn_mfma_f32_16x16x32_bf16(           \
            AF[m_], BF[n_], acc[M0 + m_][n_], 0, 0, 0);

#define G2_TILE(S, KB, STG, LAST) do {                                        \
    bf16x8 af[4], bv[4];                                                      \
    G2_LDA(af, S, 0, 0); G2_LDB(bv, S, 0);                                    \
    if (STG) G2_STGA((S) ^ 1, 0, KB);                                         \
    barrier_raw(); LGKM0(); SCHED0();                                         \
    PRIO1(); G2_MM(0, af, bv); PRIO0(); barrier_raw();                        \
    G2_LDA(af, S, 0, 4);                                                      \
    if (STG) G2_STGB((S) ^ 1, 0, KB);                                         \
    if (LAST) { WAITV(0); } else { WAITV(4); }                                \
    barrier_raw(); LGKM0(); SCHED0();                                         \
    PRIO1(); G2_MM(4, af, bv); PRIO0(); barrier_raw();                        \
    G2_LDA(af, S, 1, 0); G2_LDB(bv, S, 1);                                    \
    if (STG) G2_STGA((S) ^ 1, 1, KB);                                         \
    barrier_raw(); LGKM0(); SCHED0();                                         \
    PRIO1(); G2_MM(0, af, bv); PRIO0(); barrier_raw();                        \
    G2_LDA(af, S, 1, 4);                                                      \
    if (STG) G2_STGB((S) ^ 1, 1, KB);                                         \
    if (!LAST) { WAITV(4); }                                                  \
    barrier_raw(); LGKM0(); SCHED0();                                         \
    PRIO1(); G2_MM(4, af, bv); PRIO0(); barrier_raw();                        \
} while (0)

    G2_STGA(0, 0, 0); G2_STGB(0, 0, 0); G2_STGA(0, 1, 0); G2_STGB(0, 1, 0);
    WAITV(0);
    barrier_raw();

    int kb = 64;
    for (int it = 0; it < 7; ++it) {
        G2_TILE(0, kb, 1, 0); kb += 64;
        G2_TILE(1, kb, 1, 0); kb += 64;
    }
    G2_TILE(0, kb, 1, 0);   // tile 14
    G2_TILE(1, 0, 0, 1);    // tile 15

#undef G2_STGA
#undef G2_STGB
#undef G2_LDA
#undef G2_LDB
#undef G2_MM
#undef G2_TILE

#pragma unroll
    for (int mf = 0; mf < 8; ++mf) {
        const int gr = goff + mt + wm * 128 + mf * 16 + lq * 4;
#pragma unroll
        for (int nf = 0; nf < 4; ++nf) {
            const int col = n0 + q * 64 + nf * 16 + l15;
#pragma unroll
            for (int r = 0; r < 4; ++r)
                Z[(size_t)(gr + r) * CC + col] = (__bf16)acc[mf][nf][r];
        }
    }
}

// ---------------------------------------------------------------------------
// k_combine: out[t,c] = w1*Z[r1,c] + w2*Z[r2,c], transposed to (B,C,H,W).
// ---------------------------------------------------------------------------
__global__ __launch_bounds__(256) void k_combine(const __bf16* __restrict__ Z,
                                                 const int* __restrict__ off,
                                                 const int* __restrict__ tokE,
                                                 const int* __restrict__ tokP,
                                                 const float* __restrict__ tokW,
                                                 float* __restrict__ out) {
    __shared__ float tile[32][33];
    const int t0 = blockIdx.x * 32;
    const int c0 = blockIdx.y * 32;
    const int tx = threadIdx.x & 31;
    const int ty = threadIdx.x >> 5;

#pragma unroll
    for (int i = 0; i < 4; ++i) {
        const int tl = ty + 8 * i;
        const int t  = t0 + tl;
        const int ee = tokE[t];
        const int e1 = ee & 0xff, e2 = ee >> 8;
        const int r1 = off[e1] + tokP[2 * t];
        const int r2 = off[e2] + tokP[2 * t + 1];
        const float v = tokW[2 * t]     * (float)Z[(size_t)r1 * CC + c0 + tx]
                      + tokW[2 * t + 1] * (float)Z[(size_t)r2 * CC + c0 + tx];
        tile[tl][tx] = v;
    }
    __syncthreads();

    const int b   = t0 >> 12;
    const int hw0 = t0 & 4095;
#pragma unroll
    for (int i = 0; i < 4; ++i) {
        const int cl = ty + 8 * i;
        out[(size_t)b * CC * HWH + (size_t)(c0 + cl) * HWH + hw0 + tx] = tile[tx][cl];
    }
}

// ---------------------------------------------------------------------------
extern "C" void kernel_launch(void* const* d_in, const int* in_sizes, int n_in,
                              void* d_out, int out_size, void* d_ws, size_t ws_size,
                              hipStream_t stream) {
    const float* hs     = (const float*)d_in[0];
    const float* gate_w = (const float*)d_in[1];
    const float* w1     = (const float*)d_in[2];
    const float* w2     = (const float*)d_in[3];
    const float* w3     = (const float*)d_in[4];
    float* out = (float*)d_out;

    const size_t WSZ = (size_t)EE * FFN * CC * 2;   // 16 MB per bf16 weight
    char* ws = (char*)d_ws;
    __bf16* w2b  = (__bf16*)ws;                     // [0, 16M)   live: gemm2
    __bf16* w1b  = (__bf16*)(ws + WSZ);             // [16M,32M)  live: gemm1
    __bf16* w3b  = (__bf16*)(ws + 2 * WSZ);         // [32M,48M)  live: gemm1
    __bf16* X    = (__bf16*)(ws + 3 * WSZ);         // [48M,64M)  live: gemm1
    __bf16* Zbuf = (__bf16*)(ws + WSZ);             // overlays w1b,w3b,X-head
    __bf16* Hbuf = (__bf16*)(ws + 4 * WSZ);         // ~35.5 MiB
    float*  logP = (float*)Hbuf;                    // 4 MB, dead before gemm1
    char* p = ws + 4 * WSZ + (size_t)HCAP * FFN * 2;
    int*   idxl  = (int*)p;           p += (size_t)EE * TT * 4;
    int*   tokE  = (int*)p;           p += (size_t)TT * 4;
    int*   tokP  = (int*)p;           p += (size_t)2 * TT * 4;
    float* tokW  = (float*)p;         p += (size_t)2 * TT * 4;
    int*   cnt   = (int*)p;           p += 256;
    int*   off   = (int*)p;           p += 256;
    int*   tileE = (int*)p;           p += MAXTILES * 4;
    int*   tileM = (int*)p;           p += MAXTILES * 4;
    int*   nT    = (int*)p;

    hipMemsetAsync(cnt, 0, EE * sizeof(int), stream);

    k_prep<<<CVB + XPB + RTB, 256, 0, stream>>>(
        hs, gate_w, w1, w2, w3, w1b, w2b, w3b, X, logP);
    k_top2<<<TT / 256, 256, 0, stream>>>(logP, cnt, idxl, tokE, tokP, tokW);
    k_offsets<<<1, 64, 0, stream>>>(cnt, off, tileE, tileM, nT);

    k_gemm1<<<dim3(FFN / 128, MAXTILES), 512, 0, stream>>>(
        X, w1b, w3b, cnt, off, idxl, tileE, tileM, nT, Hbuf);
    k_gemm2<<<dim3(CC / 256, MAXTILES), 512, 0, stream>>>(
        Hbuf, w2b, off, tileE, tileM, nT, Zbuf);
    k_combine<<<dim3(TT / 32, CC / 32), 256, 0, stream>>>(
        Zbuf, off, tokE, tokP, tokW, out);
}

// Round 3
// 355.265 us; speedup vs baseline: 1.0794x; 1.0720x over previous
//
#include <hip/hip_runtime.h>
#include <hip/hip_bf16.h>
#include <math.h>

// Problem constants
#define BB 2
#define CC 1024
#define HH 64
#define WW 64
#define HWH (HH*WW)          // 4096
#define TT (BB*HWH)          // 8192 tokens
#define EE 8
#define FFN 1024
// 256-row m-tiles: sum_e ceil(cnt_e/256) <= 16384/256 + (E-1) = 71
#define MAXTILES 71
#define HCAP (MAXTILES*256)  // 18176 padded rows

typedef __bf16 bf16x8 __attribute__((ext_vector_type(8)));
typedef float  f32x4  __attribute__((ext_vector_type(4)));

// async global->LDS, 16B per lane. LDS dest = wave-uniform base + lane*16.
__device__ __forceinline__ void gl_lds16(const __bf16* g, __bf16* l) {
    __builtin_amdgcn_global_load_lds(
        (const __attribute__((address_space(1))) void*)g,
        (__attribute__((address_space(3))) void*)l, 16, 0, 0);
}

__device__ __forceinline__ void barrier_raw() {
    asm volatile("" ::: "memory");
    __builtin_amdgcn_s_barrier();
    asm volatile("" ::: "memory");
}

// bijective XCD chunk swizzle (m204): consecutive work-ids -> same XCD chunk.
__device__ __forceinline__ int xcd_swz(int orig, int nwg) {
    const int q = nwg >> 3, r = nwg & 7, x = orig & 7, o8 = orig >> 3;
    return (x < r ? x * (q + 1) : r * (q + 1) + (x - r) * q) + o8;
}

// fast exact-enough GELU (tanh form): max |diff vs erf-GELU| ~7e-4, below
// bf16 ulp of H. exp2-based: gelu(a) = a / (1 + exp(-1.5957691*(a+0.044715a^3)))
__device__ __forceinline__ float gelu_fast(float a) {
    const float a2 = a * a;
    const float t  = a * fmaf(0.044715f, a2, 1.0f);
    const float u  = __builtin_amdgcn_exp2f(t * -2.30220795f);
    return a * __builtin_amdgcn_rcpf(1.0f + u);
}

#define WAITV(N) asm volatile("s_waitcnt vmcnt(" #N ")" ::: "memory")
#define LGKM0()  asm volatile("s_waitcnt lgkmcnt(0)" ::: "memory")
#define SCHED0() __builtin_amdgcn_sched_barrier(0)
#define PRIO1()  __builtin_amdgcn_s_setprio(1)
#define PRIO0()  __builtin_amdgcn_s_setprio(0)

// ---------------------------------------------------------------------------
// k_prep: one launch doing (a) w1/w2/w3 fp32->bf16, (b) hs transpose -> X bf16,
// (c) router partial logits (16-way K-split).  All memory-bound, overlapped.
// ---------------------------------------------------------------------------
#define CVB 12288
#define XPB 8192
#define RTB 512
__global__ __launch_bounds__(256) void k_prep(
    const float* __restrict__ hs, const float* __restrict__ gate_w,
    const float* __restrict__ w1, const float* __restrict__ w2,
    const float* __restrict__ w3,
    __bf16* __restrict__ w1b, __bf16* __restrict__ w2b,
    __bf16* __restrict__ w3b, __bf16* __restrict__ X,
    float* __restrict__ logP) {
    __shared__ float sm[2112];   // union: xpose tile 32x33 | router gate 8x256
    const int bid = blockIdx.x;
    const int tid = threadIdx.x;

    if (bid < CVB) {
        // --- weight convert: 8 elems/thread ---
        const float* s; __bf16* d; int lb = bid;
        if (lb < 4096)      { s = w1; d = w1b; }
        else if (lb < 8192) { s = w2; d = w2b; lb -= 4096; }
        else                { s = w3; d = w3b; lb -= 8192; }
        const size_t i = (size_t)lb * 2048 + (size_t)tid * 8;
        const f32x4 v0 = *(const f32x4*)&s[i];
        const f32x4 v1 = *(const f32x4*)&s[i + 4];
        bf16x8 o;
#pragma unroll
        for (int j = 0; j < 4; ++j) { o[j] = (__bf16)v0[j]; o[4 + j] = (__bf16)v1[j]; }
        *(bf16x8*)&d[i] = o;
    } else if (bid < CVB + XPB) {
        // --- transpose hs (B,C,H,W) -> X [T,C] bf16 ---
        const int lb  = bid - CVB;
        const int hw0 = (lb & 127) * 32;
        const int c0  = ((lb >> 7) & 31) * 32;
        const int b   = lb >> 12;
        float (*tile)[33] = (float(*)[33])sm;
        const int tx = tid & 31, ty = tid >> 5;
        const float* src = hs + ((size_t)b * CC + c0) * HWH + hw0;
#pragma unroll
        for (int i = 0; i < 4; ++i)
            tile[ty + i * 8][tx] = src[(size_t)(ty + i * 8) * HWH + tx];
        __syncthreads();
        __bf16* dst = X + ((size_t)b * HWH + hw0) * CC + c0;
#pragma unroll
        for (int i = 0; i < 4; ++i) {
            const int hwl = ty + i * 8;
            dst[(size_t)hwl * CC + tx] = (__bf16)tile[tx][hwl];
        }
    } else {
        // --- router partial: block = (tokblk, quarter q); thread = (q2, token) ---
        const int lb  = bid - (CVB + XPB);
        const int q   = lb & 3;
        const int t64 = lb >> 2;
        float* g = sm;   // [8][256] slice of gate for channels [q*256, +256)
        for (int i = tid; i < 2048; i += 256)
            g[i] = gate_w[(size_t)(i >> 8) * CC + q * 256 + (i & 255)];
        __syncthreads();
        const int q2 = tid >> 6, tl = tid & 63;
        const int t  = t64 * 64 + tl;
        const int b  = t >> 12, hw = t & 4095;
        const float* xp = hs + (size_t)b * CC * HWH + hw;
        float l[EE];
#pragma unroll
        for (int e = 0; e < EE; ++e) l[e] = 0.0f;
        const int cbase = q * 256 + q2 * 64;
        for (int c2 = 0; c2 < 64; ++c2) {
            const float xv = xp[(size_t)(cbase + c2) * HWH];
#pragma unroll
            for (int e = 0; e < EE; ++e) l[e] += xv * g[e * 256 + q2 * 64 + c2];
        }
        float* dst = logP + ((size_t)(q * 4 + q2) * TT + t) * 8;
        f32x4 a, c;
#pragma unroll
        for (int e = 0; e < 4; ++e) { a[e] = l[e]; c[e] = l[4 + e]; }
        *(f32x4*)dst = a;
        *(f32x4*)&dst[4] = c;
    }
}

// ---------------------------------------------------------------------------
// k_top2: reduce 16 partials, top-2, renormalize, block-aggregated atomics.
// ---------------------------------------------------------------------------
__global__ __launch_bounds__(256) void k_top2(const float* __restrict__ logP,
                                              int* __restrict__ cnt,
                                              int* __restrict__ idxl,
                                              int* __restrict__ tokE,
                                              int* __restrict__ tokP,
                                              float* __restrict__ tokW) {
    __shared__ int lcnt[EE], lbase[EE];
    const int tid = threadIdx.x;
    const int t   = blockIdx.x * 256 + tid;
    if (tid < EE) lcnt[tid] = 0;
    __syncthreads();

    float l[EE];
#pragma unroll
    for (int e = 0; e < EE; ++e) l[e] = 0.0f;
#pragma unroll
    for (int pq = 0; pq < 16; ++pq) {
        const float* src = logP + ((size_t)pq * TT + t) * 8;
        const f32x4 a = *(const f32x4*)src;
        const f32x4 c = *(const f32x4*)&src[4];
#pragma unroll
        for (int e = 0; e < 4; ++e) { l[e] += a[e]; l[4 + e] += c[e]; }
    }

    int e1 = 0; float v1 = l[0];
#pragma unroll
    for (int e = 1; e < EE; ++e) { if (l[e] > v1) { v1 = l[e]; e1 = e; } }
    int e2 = -1; float v2 = -1e30f;
#pragma unroll
    for (int e = 0; e < EE; ++e) { if (e != e1 && l[e] > v2) { v2 = l[e]; e2 = e; } }

    const float p2 = __expf(v2 - v1);
    const float rs = 1.0f / (1.0f + p2);

    const int m1 = atomicAdd(&lcnt[e1], 1);
    const int m2 = atomicAdd(&lcnt[e2], 1);
    __syncthreads();
    if (tid < EE) lbase[tid] = atomicAdd(&cnt[tid], lcnt[tid]);
    __syncthreads();
    const int p1pos = lbase[e1] + m1;
    const int p2pos = lbase[e2] + m2;

    idxl[e1 * TT + p1pos] = t;
    idxl[e2 * TT + p2pos] = t;
    tokE[t] = e1 | (e2 << 8);
    tokP[2 * t]     = p1pos;
    tokP[2 * t + 1] = p2pos;
    tokW[2 * t]     = rs;
    tokW[2 * t + 1] = p2 * rs;
}

// ---------------------------------------------------------------------------
// GEMM1: H = gelu(X@W1^T)*(X@W3^T), bf16, grouped.  Loop structure identical
// to R2 (BM=256,BK=64, 8 waves, per-wave 128x64, 4 phases/K-tile, vmcnt(4)).
// New: inline tile map from cnt (k_offsets deleted), XCD swizzle, fast gelu.
// grid (FFN/128, MAXTILES).
// ---------------------------------------------------------------------------
__global__ __launch_bounds__(512, 1)
void k_gemm1(const __bf16* __restrict__ X, const __bf16* __restrict__ w1b,
             const __bf16* __restrict__ w3b, const int* __restrict__ cnt,
             const int* __restrict__ idxl, __bf16* __restrict__ H) {
    // --- XCD swizzle + inline (expert, m-tile) map ---
    const int lid = blockIdx.y * 8 + blockIdx.x;
    const int wg  = xcd_swz(lid, 8 * MAXTILES);
    const int n0  = (wg & 7) * 128;          // H-column base
    int ty = wg >> 3;
    int e = -1, mt = 0, goff = 0, acc_rows = 0;
#pragma unroll
    for (int ee = 0; ee < EE; ++ee) {
        const int me = (cnt[ee] + 255) >> 8;
        if (ty >= 0 && ty < me) { e = ee; mt = ty << 8; goff = acc_rows; }
        ty -= me;
        acc_rows += me << 8;
    }
    if (e < 0) return;
    const int cntE = cnt[e];
    const __bf16* W1 = w1b + (size_t)e * FFN * CC;
    const __bf16* W3 = w3b + (size_t)e * FFN * CC;

    __shared__ __align__(16) __bf16 sA[2][2][256 * 32];   // [slot][khalf] 64 KB
    __shared__ __align__(16) __bf16 sB[2][2][256 * 32];   // 64 KB

    const int tid  = threadIdx.x;
    const int lane = tid & 63, wave = tid >> 6;
    const int l15  = lane & 15, lq = lane >> 4;
    const int wm   = wave & 1;     // m-half (rows wm*128..)
    const int q    = wave >> 1;    // n-quarter
    const int rsw  = (lq ^ ((l15 >> 1) & 3)) * 8;       // frag-read swizzled chunk

    // staging mapping: lane -> row (lane>>2), chunk-slot (lane&3)
    const int rl  = lane >> 2;
    const int csw = ((lane & 3) ^ ((rl >> 1) & 3)) * 8;  // pre-swizzled global chunk

    // A: gathered token rows mt + wave*32 + {0,16} + rl (clamped to cntE-1)
    int pr0 = mt + wave * 32 + rl;       if (pr0 > cntE - 1) pr0 = cntE - 1;
    int pr1 = mt + wave * 32 + 16 + rl;  if (pr1 > cntE - 1) pr1 = cntE - 1;
    const __bf16* gA0 = X + (size_t)idxl[e * TT + pr0] * CC + csw;
    const __bf16* gA1 = X + (size_t)idxl[e * TT + pr1] * CC + csw;
    // B: wave even -> W1, wave odd -> W3; cols n0 + (wave>>1)*32 + {0,16} + rl
    const __bf16* WB = (wave & 1) ? W3 : W1;
    const __bf16* gB0 = WB + (size_t)(n0 + q * 32 + rl) * CC + csw;
    const __bf16* gB1 = WB + (size_t)(n0 + q * 32 + 16 + rl) * CC + csw;

    const int st0  = wave * 1024;                 // stage LDS base (elems)
    const int aoff = (wm * 128 + l15) * 32 + rsw; // + mf*512
    const int boff = (q * 64 + l15) * 32 + rsw;   // + nf*512

    f32x4 acc[8][4] = {};

#define G1_STGA(S, KS, KB) do {                                               \
    gl_lds16(gA0 + (KB) + (KS) * 32, &sA[S][KS][st0]);                        \
    gl_lds16(gA1 + (KB) + (KS) * 32, &sA[S][KS][st0 + 512]); } while (0)
#define G1_STGB(S, KS, KB) do {                                               \
    gl_lds16(gB0 + (KB) + (KS) * 32, &sB[S][KS][st0]);                        \
    gl_lds16(gB1 + (KB) + (KS) * 32, &sB[S][KS][st0 + 512]); } while (0)
#define G1_LDA(DST, S, KS, MF0)                                               \
    _Pragma("unroll") for (int mf_ = 0; mf_ < 4; ++mf_)                       \
        DST[mf_] = *(const bf16x8*)&sA[S][KS][aoff + (MF0 + mf_) * 512];
#define G1_LDB(DST, S, KS)                                                    \
    _Pragma("unroll") for (int nf_ = 0; nf_ < 4; ++nf_)                       \
        DST[nf_] = *(const bf16x8*)&sB[S][KS][boff + nf_ * 512];
#define G1_MM(M0, AF, BF)                                                     \
    _Pragma("unroll") for (int m_ = 0; m_ < 4; ++m_)                          \
    _Pragma("unroll") for (int n_ = 0; n_ < 4; ++n_)                          \
        acc[M0 + m_][n_] = __builtin_amdgcn_mfma_f32_16x16x32_bf16(           \
            AF[m_], BF[n_], acc[M0 + m_][n_], 0, 0, 0);

#define G1_TILE(S, KB, STG, LAST) do {                                        \
    bf16x8 af[4], bv[4];                                                      \
    /* phase 1: ks0, m-frags 0-3 (+ all B ks0) */                             \
    G1_LDA(af, S, 0, 0); G1_LDB(bv, S, 0);                                    \
    if (STG) G1_STGA((S) ^ 1, 0, KB);                                         \
    barrier_raw(); LGKM0(); SCHED0();                                         \
    PRIO1(); G1_MM(0, af, bv); PRIO0(); barrier_raw();                        \
    /* phase 2: ks0, m-frags 4-7 */                                           \
    G1_LDA(af, S, 0, 4);                                                      \
    if (STG) G1_STGB((S) ^ 1, 0, KB);                                         \
    if (LAST) { WAITV(0); } else { WAITV(4); }                                \
    barrier_raw(); LGKM0(); SCHED0();                                         \
    PRIO1(); G1_MM(4, af, bv); PRIO0(); barrier_raw();                        \
    /* phase 3: ks1, m-frags 0-3 (+ all B ks1) */                             \
    G1_LDA(af, S, 1, 0); G1_LDB(bv, S, 1);                                    \
    if (STG) G1_STGA((S) ^ 1, 1, KB);                                         \
    barrier_raw(); LGKM0(); SCHED0();                                         \
    PRIO1(); G1_MM(0, af, bv); PRIO0(); barrier_raw();                        \
    /* phase 4: ks1, m-frags 4-7 */                                           \
    G1_LDA(af, S, 1, 4);                                                      \
    if (STG) G1_STGB((S) ^ 1, 1, KB);                                         \
    if (!LAST) { WAITV(4); }                                                  \
    barrier_raw(); LGKM0(); SCHED0();                                         \
    PRIO1(); G1_MM(4, af, bv); PRIO0(); barrier_raw();                        \
} while (0)

    // prologue: tile0 -> slot0, full drain once
    G1_STGA(0, 0, 0); G1_STGB(0, 0, 0); G1_STGA(0, 1, 0); G1_STGB(0, 1, 0);
    WAITV(0);
    barrier_raw();

    int kb = 64;   // element offset of tile being prefetched
    for (int it = 0; it < 7; ++it) {
        G1_TILE(0, kb, 1, 0); kb += 64;
        G1_TILE(1, kb, 1, 0); kb += 64;
    }
    G1_TILE(0, kb, 1, 0);   // tile 14, stages tile 15 (kb=960)
    G1_TILE(1, 0, 0, 1);    // tile 15, no stage, final drain at phase 2

#undef G1_STGA
#undef G1_STGB
#undef G1_LDA
#undef G1_LDB
#undef G1_MM
#undef G1_TILE

    // epilogue: acc[mf][jp] (W1) pairs with acc[mf][jp+2] (W3), same H-col
#pragma unroll
    for (int mf = 0; mf < 8; ++mf) {
        const int gr = goff + mt + wm * 128 + mf * 16 + lq * 4;
#pragma unroll
        for (int jp = 0; jp < 2; ++jp) {
            const int col = n0 + q * 32 + jp * 16 + l15;
#pragma unroll
            for (int r = 0; r < 4; ++r) {
                const float a  = acc[mf][jp][r];
                const float c  = acc[mf][jp + 2][r];
                H[(size_t)(gr + r) * FFN + col] = (__bf16)(gelu_fast(a) * c);
            }
        }
    }
}

// ---------------------------------------------------------------------------
// GEMM2: Z = H @ W2^T, bf16, grouped. Same loop as R2; inline map + swizzle.
// grid (CC/256, MAXTILES).
// ---------------------------------------------------------------------------
__global__ __launch_bounds__(512, 1)
void k_gemm2(const __bf16* __restrict__ H, const __bf16* __restrict__ w2b,
             const int* __restrict__ cnt, __bf16* __restrict__ Z) {
    const int lid = blockIdx.y * 4 + blockIdx.x;
    const int wg  = xcd_swz(lid, 4 * MAXTILES);
    const int n0  = (wg & 3) * 256;
    int ty = wg >> 2;
    int e = -1, mt = 0, goff = 0, acc_rows = 0;
#pragma unroll
    for (int ee = 0; ee < EE; ++ee) {
        const int me = (cnt[ee] + 255) >> 8;
        if (ty >= 0 && ty < me) { e = ee; mt = ty << 8; goff = acc_rows; }
        ty -= me;
        acc_rows += me << 8;
    }
    if (e < 0) return;
    const __bf16* W2 = w2b + (size_t)e * CC * FFN;
    const __bf16* Ar = H + (size_t)(goff + mt) * FFN;

    __shared__ __align__(16) __bf16 sA[2][2][256 * 32];
    __shared__ __align__(16) __bf16 sB[2][2][256 * 32];

    const int tid  = threadIdx.x;
    const int lane = tid & 63, wave = tid >> 6;
    const int l15  = lane & 15, lq = lane >> 4;
    const int wm   = wave & 1;
    const int q    = wave >> 1;
    const int rsw  = (lq ^ ((l15 >> 1) & 3)) * 8;
    const int rl   = lane >> 2;
    const int csw  = ((lane & 3) ^ ((rl >> 1) & 3)) * 8;

    const __bf16* gA0 = Ar + (size_t)(wave * 32 + rl) * FFN + csw;
    const __bf16* gA1 = Ar + (size_t)(wave * 32 + 16 + rl) * FFN + csw;
    const __bf16* gB0 = W2 + (size_t)(n0 + wave * 32 + rl) * FFN + csw;
    const __bf16* gB1 = W2 + (size_t)(n0 + wave * 32 + 16 + rl) * FFN + csw;

    const int st0  = wave * 1024;
    const int aoff = (wm * 128 + l15) * 32 + rsw;
    const int boff = (q * 64 + l15) * 32 + rsw;

    f32x4 acc[8][4] = {};

#define G2_STGA(S, KS, KB) do {                                               \
    gl_lds16(gA0 + (KB) + (KS) * 32, &sA[S][KS][st0]);                        \
    gl_lds16(gA1 + (KB) + (KS) * 32, &sA[S][KS][st0 + 512]); } while (0)
#define G2_STGB(S, KS, KB) do {                                               \
    gl_lds16(gB0 + (KB) + (KS) * 32, &sB[S][KS][st0]);                        \
    gl_lds16(gB1 + (KB) + (KS) * 32, &sB[S][KS][st0 + 512]); } while (0)
#define G2_LDA(DST, S, KS, MF0)                                               \
    _Pragma("unroll") for (int mf_ = 0; mf_ < 4; ++mf_)                       \
        DST[mf_] = *(const bf16x8*)&sA[S][KS][aoff + (MF0 + mf_) * 512];
#define G2_LDB(DST, S, KS)                                                    \
    _Pragma("unroll") for (int nf_ = 0; nf_ < 4; ++nf_)                       \
        DST[nf_] = *(const bf16x8*)&sB[S][KS][boff + nf_ * 512];
#define G2_MM(M0, AF, BF)                                                     \
    _Pragma("unroll") for (int m_ = 0; m_ < 4; ++m_)                          \
    _Pragma("unroll") for (int n_ = 0; n_ < 4; ++n_)                          \
        acc[M0 + m_][n_] = __builtin_amdgcn_mfma_f32_16x16x32_bf16(           \
            AF[m_], BF[n_], acc[M0 + m_][n_], 0, 0, 0);

#define G2_TILE(S, KB, STG, LAST) do {                                        \
    bf16x8 af[4], bv[4];                                                      \
    G2_LDA(af, S, 0, 0); G2_LDB(bv, S, 0);                                    \
    if (STG) G2_STGA((S) ^ 1, 0, KB);                                         \
    barrier_raw(); LGKM0(); SCHED0();                                         \
    PRIO1(); G2_MM(0, af, bv); PRIO0(); barrier_raw();                        \
    G2_LDA(af, S, 0, 4);                                                      \
    if (STG) G2_STGB((S) ^ 1, 0, KB);                                         \
    if (LAST) { WAITV(0); } else { WAITV(4); }                                \
    barrier_raw(); LGKM0(); SCHED0();                                         \
    PRIO1(); G2_MM(4, af, bv); PRIO0(); barrier_raw();                        \
    G2_LDA(af, S, 1, 0); G2_LDB(bv, S, 1);                                    \
    if (STG) G2_STGA((S) ^ 1, 1, KB);                                         \
    barrier_raw(); LGKM0(); SCHED0();                                         \
    PRIO1(); G2_MM(0, af, bv); PRIO0(); barrier_raw();                        \
    G2_LDA(af, S, 1, 4);                                                      \
    if (STG) G2_STGB((S) ^ 1, 1, KB);                                         \
    if (!LAST) { WAITV(4); }                                                  \
    barrier_raw(); LGKM0(); SCHED0();                                         \
    PRIO1(); G2_MM(4, af, bv); PRIO0(); barrier_raw();                        \
} while (0)

    G2_STGA(0, 0, 0); G2_STGB(0, 0, 0); G2_STGA(0, 1, 0); G2_STGB(0, 1, 0);
    WAITV(0);
    barrier_raw();

    int kb = 64;
    for (int it = 0; it < 7; ++it) {
        G2_TILE(0, kb, 1, 0); kb += 64;
        G2_TILE(1, kb, 1, 0); kb += 64;
    }
    G2_TILE(0, kb, 1, 0);   // tile 14
    G2_TILE(1, 0, 0, 1);    // tile 15

#undef G2_STGA
#undef G2_STGB
#undef G2_LDA
#undef G2_LDB
#undef G2_MM
#undef G2_TILE

#pragma unroll
    for (int mf = 0; mf < 8; ++mf) {
        const int gr = goff + mt + wm * 128 + mf * 16 + lq * 4;
#pragma unroll
        for (int nf = 0; nf < 4; ++nf) {
            const int col = n0 + q * 64 + nf * 16 + l15;
#pragma unroll
            for (int r = 0; r < 4; ++r)
                Z[(size_t)(gr + r) * CC + col] = (__bf16)acc[mf][nf][r];
        }
    }
}

// ---------------------------------------------------------------------------
// k_combine: out[t,c] = w1*Z[r1,c] + w2*Z[r2,c], transposed to (B,C,H,W).
// Expert row offsets computed inline from cnt (k_offsets deleted).
// ---------------------------------------------------------------------------
__global__ __launch_bounds__(256) void k_combine(const __bf16* __restrict__ Z,
                                                 const int* __restrict__ cnt,
                                                 const int* __restrict__ tokE,
                                                 const int* __restrict__ tokP,
                                                 const float* __restrict__ tokW,
                                                 float* __restrict__ out) {
    __shared__ float tile[32][33];
    __shared__ int s_pre[EE];
    const int tid = threadIdx.x;
    if (tid < EE) {
        int a = 0;
        for (int ee = 0; ee < tid; ++ee) a += ((cnt[ee] + 255) >> 8) << 8;
        s_pre[tid] = a;
    }
    __syncthreads();

    const int t0 = blockIdx.x * 32;
    const int c0 = blockIdx.y * 32;
    const int tx = tid & 31;
    const int ty = tid >> 5;

#pragma unroll
    for (int i = 0; i < 4; ++i) {
        const int tl = ty + 8 * i;
        const int t  = t0 + tl;
        const int ee = tokE[t];
        const int e1 = ee & 0xff, e2 = ee >> 8;
        const int r1 = s_pre[e1] + tokP[2 * t];
        const int r2 = s_pre[e2] + tokP[2 * t + 1];
        const float v = tokW[2 * t]     * (float)Z[(size_t)r1 * CC + c0 + tx]
                      + tokW[2 * t + 1] * (float)Z[(size_t)r2 * CC + c0 + tx];
        tile[tl][tx] = v;
    }
    __syncthreads();

    const int b   = t0 >> 12;
    const int hw0 = t0 & 4095;
#pragma unroll
    for (int i = 0; i < 4; ++i) {
        const int cl = ty + 8 * i;
        out[(size_t)b * CC * HWH + (size_t)(c0 + cl) * HWH + hw0 + tx] = tile[tx][cl];
    }
}

// ---------------------------------------------------------------------------
extern "C" void kernel_launch(void* const* d_in, const int* in_sizes, int n_in,
                              void* d_out, int out_size, void* d_ws, size_t ws_size,
                              hipStream_t stream) {
    const float* hs     = (const float*)d_in[0];
    const float* gate_w = (const float*)d_in[1];
    const float* w1     = (const float*)d_in[2];
    const float* w2     = (const float*)d_in[3];
    const float* w3     = (const float*)d_in[4];
    float* out = (float*)d_out;

    const size_t WSZ = (size_t)EE * FFN * CC * 2;   // 16 MB per bf16 weight
    char* ws = (char*)d_ws;
    __bf16* w2b  = (__bf16*)ws;                     // [0, 16M)   live: gemm2
    __bf16* w1b  = (__bf16*)(ws + WSZ);             // [16M,32M)  live: gemm1
    __bf16* w3b  = (__bf16*)(ws + 2 * WSZ);         // [32M,48M)  live: gemm1
    __bf16* X    = (__bf16*)(ws + 3 * WSZ);         // [48M,64M)  live: gemm1
    __bf16* Zbuf = (__bf16*)(ws + WSZ);             // overlays w1b,w3b,X-head
    __bf16* Hbuf = (__bf16*)(ws + 4 * WSZ);         // ~35.5 MiB
    float*  logP = (float*)Hbuf;                    // 4 MB, dead before gemm1
    char* p = ws + 4 * WSZ + (size_t)HCAP * FFN * 2;
    int*   idxl  = (int*)p;           p += (size_t)EE * TT * 4;
    int*   tokE  = (int*)p;           p += (size_t)TT * 4;
    int*   tokP  = (int*)p;           p += (size_t)2 * TT * 4;
    float* tokW  = (float*)p;         p += (size_t)2 * TT * 4;
    int*   cnt   = (int*)p;           p += 256;

    hipMemsetAsync(cnt, 0, EE * sizeof(int), stream);

    k_prep<<<CVB + XPB + RTB, 256, 0, stream>>>(
        hs, gate_w, w1, w2, w3, w1b, w2b, w3b, X, logP);
    k_top2<<<TT / 256, 256, 0, stream>>>(logP, cnt, idxl, tokE, tokP, tokW);

    k_gemm1<<<dim3(FFN / 128, MAXTILES), 512, 0, stream>>>(
        X, w1b, w3b, cnt, idxl, Hbuf);
    k_gemm2<<<dim3(CC / 256, MAXTILES), 512, 0, stream>>>(
        Hbuf, w2b, cnt, Zbuf);
    k_combine<<<dim3(TT / 32, CC / 32), 256, 0, stream>>>(
        Zbuf, cnt, tokE, tokP, tokW, out);
}

// Round 4
// 329.759 us; speedup vs baseline: 1.1629x; 1.0773x over previous
//
#include <hip/hip_runtime.h>
#include <hip/hip_bf16.h>
#include <math.h>

// Problem constants
#define BB 2
#define CC 1024
#define HH 64
#define WW 64
#define HWH (HH*WW)          // 4096
#define TT (BB*HWH)          // 8192 tokens
#define EE 8
#define FFN 1024
// 256-row m-tiles: sum_e ceil(cnt_e/256) <= 16384/256 + (E-1) = 71
#define MAXTILES 71
#define HCAP (MAXTILES*256)  // 18176 padded rows

typedef __bf16 bf16x8 __attribute__((ext_vector_type(8)));
typedef float  f32x4  __attribute__((ext_vector_type(4)));

// async global->LDS, 16B per lane. LDS dest = wave-uniform base + lane*16.
__device__ __forceinline__ void gl_lds16(const __bf16* g, __bf16* l) {
    __builtin_amdgcn_global_load_lds(
        (const __attribute__((address_space(1))) void*)g,
        (__attribute__((address_space(3))) void*)l, 16, 0, 0);
}

__device__ __forceinline__ void barrier_raw() {
    asm volatile("" ::: "memory");
    __builtin_amdgcn_s_barrier();
    asm volatile("" ::: "memory");
}

// bijective XCD chunk swizzle (m204): consecutive work-ids -> same XCD chunk.
__device__ __forceinline__ int xcd_swz(int orig, int nwg) {
    const int q = nwg >> 3, r = nwg & 7, x = orig & 7, o8 = orig >> 3;
    return (x < r ? x * (q + 1) : r * (q + 1) + (x - r) * q) + o8;
}

// fast exact-enough GELU (tanh form): max |diff vs erf-GELU| ~7e-4, below
// bf16 ulp of H. exp2-based: gelu(a) = a / (1 + exp(-1.5957691*(a+0.044715a^3)))
__device__ __forceinline__ float gelu_fast(float a) {
    const float a2 = a * a;
    const float t  = a * fmaf(0.044715f, a2, 1.0f);
    const float u  = __builtin_amdgcn_exp2f(t * -2.30220795f);
    return a * __builtin_amdgcn_rcpf(1.0f + u);
}

#define WAITV(N) asm volatile("s_waitcnt vmcnt(" #N ")" ::: "memory")
#define LGKM0()  asm volatile("s_waitcnt lgkmcnt(0)" ::: "memory")
#define SCHED0() __builtin_amdgcn_sched_barrier(0)
#define PRIO1()  __builtin_amdgcn_s_setprio(1)
#define PRIO0()  __builtin_amdgcn_s_setprio(0)

// ---------------------------------------------------------------------------
// k_prep: one launch doing (a) w1/w2/w3 fp32->bf16, (b) hs transpose -> X bf16,
// (c) router partial logits (16-way K-split).  All memory-bound, overlapped.
// ---------------------------------------------------------------------------
#define CVB 12288
#define XPB 8192
#define RTB 512
__global__ __launch_bounds__(256) void k_prep(
    const float* __restrict__ hs, const float* __restrict__ gate_w,
    const float* __restrict__ w1, const float* __restrict__ w2,
    const float* __restrict__ w3,
    __bf16* __restrict__ w1b, __bf16* __restrict__ w2b,
    __bf16* __restrict__ w3b, __bf16* __restrict__ X,
    float* __restrict__ logP) {
    __shared__ float sm[2112];   // union: xpose tile 32x33 | router gate 8x256
    const int bid = blockIdx.x;
    const int tid = threadIdx.x;

    if (bid < CVB) {
        // --- weight convert: 8 elems/thread ---
        const float* s; __bf16* d; int lb = bid;
        if (lb < 4096)      { s = w1; d = w1b; }
        else if (lb < 8192) { s = w2; d = w2b; lb -= 4096; }
        else                { s = w3; d = w3b; lb -= 8192; }
        const size_t i = (size_t)lb * 2048 + (size_t)tid * 8;
        const f32x4 v0 = *(const f32x4*)&s[i];
        const f32x4 v1 = *(const f32x4*)&s[i + 4];
        bf16x8 o;
#pragma unroll
        for (int j = 0; j < 4; ++j) { o[j] = (__bf16)v0[j]; o[4 + j] = (__bf16)v1[j]; }
        *(bf16x8*)&d[i] = o;
    } else if (bid < CVB + XPB) {
        // --- transpose hs (B,C,H,W) -> X [T,C] bf16 ---
        const int lb  = bid - CVB;
        const int hw0 = (lb & 127) * 32;
        const int c0  = ((lb >> 7) & 31) * 32;
        const int b   = lb >> 12;
        float (*tile)[33] = (float(*)[33])sm;
        const int tx = tid & 31, ty = tid >> 5;
        const float* src = hs + ((size_t)b * CC + c0) * HWH + hw0;
#pragma unroll
        for (int i = 0; i < 4; ++i)
            tile[ty + i * 8][tx] = src[(size_t)(ty + i * 8) * HWH + tx];
        __syncthreads();
        __bf16* dst = X + ((size_t)b * HWH + hw0) * CC + c0;
#pragma unroll
        for (int i = 0; i < 4; ++i) {
            const int hwl = ty + i * 8;
            dst[(size_t)hwl * CC + tx] = (__bf16)tile[tx][hwl];
        }
    } else {
        // --- router partial: block = (tokblk, quarter q); thread = (q2, token) ---
        const int lb  = bid - (CVB + XPB);
        const int q   = lb & 3;
        const int t64 = lb >> 2;
        float* g = sm;   // [8][256] slice of gate for channels [q*256, +256)
        for (int i = tid; i < 2048; i += 256)
            g[i] = gate_w[(size_t)(i >> 8) * CC + q * 256 + (i & 255)];
        __syncthreads();
        const int q2 = tid >> 6, tl = tid & 63;
        const int t  = t64 * 64 + tl;
        const int b  = t >> 12, hw = t & 4095;
        const float* xp = hs + (size_t)b * CC * HWH + hw;
        float l[EE];
#pragma unroll
        for (int e = 0; e < EE; ++e) l[e] = 0.0f;
        const int cbase = q * 256 + q2 * 64;
        for (int c2 = 0; c2 < 64; ++c2) {
            const float xv = xp[(size_t)(cbase + c2) * HWH];
#pragma unroll
            for (int e = 0; e < EE; ++e) l[e] += xv * g[e * 256 + q2 * 64 + c2];
        }
        float* dst = logP + ((size_t)(q * 4 + q2) * TT + t) * 8;
        f32x4 a, c;
#pragma unroll
        for (int e = 0; e < 4; ++e) { a[e] = l[e]; c[e] = l[4 + e]; }
        *(f32x4*)dst = a;
        *(f32x4*)&dst[4] = c;
    }
}

// ---------------------------------------------------------------------------
// k_top2: reduce 16 partials, top-2, renormalize, block-aggregated atomics.
// ---------------------------------------------------------------------------
__global__ __launch_bounds__(256) void k_top2(const float* __restrict__ logP,
                                              int* __restrict__ cnt,
                                              int* __restrict__ idxl,
                                              int* __restrict__ tokE,
                                              int* __restrict__ tokP,
                                              float* __restrict__ tokW) {
    __shared__ int lcnt[EE], lbase[EE];
    const int tid = threadIdx.x;
    const int t   = blockIdx.x * 256 + tid;
    if (tid < EE) lcnt[tid] = 0;
    __syncthreads();

    float l[EE];
#pragma unroll
    for (int e = 0; e < EE; ++e) l[e] = 0.0f;
#pragma unroll
    for (int pq = 0; pq < 16; ++pq) {
        const float* src = logP + ((size_t)pq * TT + t) * 8;
        const f32x4 a = *(const f32x4*)src;
        const f32x4 c = *(const f32x4*)&src[4];
#pragma unroll
        for (int e = 0; e < 4; ++e) { l[e] += a[e]; l[4 + e] += c[e]; }
    }

    int e1 = 0; float v1 = l[0];
#pragma unroll
    for (int e = 1; e < EE; ++e) { if (l[e] > v1) { v1 = l[e]; e1 = e; } }
    int e2 = -1; float v2 = -1e30f;
#pragma unroll
    for (int e = 0; e < EE; ++e) { if (e != e1 && l[e] > v2) { v2 = l[e]; e2 = e; } }

    const float p2 = __expf(v2 - v1);
    const float rs = 1.0f / (1.0f + p2);

    const int m1 = atomicAdd(&lcnt[e1], 1);
    const int m2 = atomicAdd(&lcnt[e2], 1);
    __syncthreads();
    if (tid < EE) lbase[tid] = atomicAdd(&cnt[tid], lcnt[tid]);
    __syncthreads();
    const int p1pos = lbase[e1] + m1;
    const int p2pos = lbase[e2] + m2;

    idxl[e1 * TT + p1pos] = t;
    idxl[e2 * TT + p2pos] = t;
    tokE[t] = e1 | (e2 << 8);
    tokP[2 * t]     = p1pos;
    tokP[2 * t + 1] = p2pos;
    tokW[2 * t]     = rs;
    tokW[2 * t + 1] = p2 * rs;
}

// ---------------------------------------------------------------------------
// Shared GEMM tile body: 3-slot LDS ring, BK=32, 1 barrier/tile, counted
// vmcnt(3) (tile i stages tile i+2 -> 2 tiles of latency cover).
// ---------------------------------------------------------------------------
#define GT_TILE(SR, SS, KB, STG, WC) do {                                     \
    if (STG) {                                                                \
        gl_lds16(gA0 + (KB), &sA[SS][stA]);                                   \
        gl_lds16(gA1 + (KB), &sA[SS][stA + 4096]);                            \
        gl_lds16(gB0 + (KB), &sB[SS][stA]);                                   \
    }                                                                         \
    bf16x8 af[4], bv[4];                                                      \
    _Pragma("unroll") for (int f_ = 0; f_ < 4; ++f_) {                        \
        af[f_] = *(const bf16x8*)&sA[SR][aoff + f_ * 512];                    \
        bv[f_] = *(const bf16x8*)&sB[SR][boff + f_ * 512];                    \
    }                                                                         \
    LGKM0(); SCHED0();                                                        \
    PRIO1();                                                                  \
    _Pragma("unroll") for (int m_ = 0; m_ < 4; ++m_)                          \
    _Pragma("unroll") for (int n_ = 0; n_ < 4; ++n_)                          \
        acc[m_][n_] = __builtin_amdgcn_mfma_f32_16x16x32_bf16(                \
            af[m_], bv[n_], acc[m_][n_], 0, 0, 0);                            \
    PRIO0();                                                                  \
    WC;                                                                       \
    barrier_raw();                                                            \
} while (0)

// ---------------------------------------------------------------------------
// GEMM1: H = gelu(X@W1^T)*(X@W3^T), bf16, grouped.
// BM=256, BN=64 (dual weights: B-LDS = 64 W1-rows + 64 W3-rows), BK=32.
// 8 waves (4m x 2n), per-wave 64x64, acc[4][4] (64 VGPR) -> fits
// __launch_bounds__(512,4) = 2 blocks/CU.  LDS 72 KiB (3-slot ring).
// grid (FFN/64, MAXTILES).
// ---------------------------------------------------------------------------
__global__ __launch_bounds__(512, 4)
void k_gemm1(const __bf16* __restrict__ X, const __bf16* __restrict__ w1b,
             const __bf16* __restrict__ w3b, const int* __restrict__ cnt,
             const int* __restrict__ idxl, __bf16* __restrict__ H) {
    const int lid = blockIdx.y * 16 + blockIdx.x;
    const int wg  = xcd_swz(lid, 16 * MAXTILES);
    const int n0  = (wg & 15) * 64;          // H-column base
    int ty = wg >> 4;
    int e = -1, mt = 0, goff = 0, acc_rows = 0;
#pragma unroll
    for (int ee = 0; ee < EE; ++ee) {
        const int me = (cnt[ee] + 255) >> 8;
        if (ty >= 0 && ty < me) { e = ee; mt = ty << 8; goff = acc_rows; }
        ty -= me;
        acc_rows += me << 8;
    }
    if (e < 0) return;
    const int cntE = cnt[e];
    const __bf16* W1 = w1b + (size_t)e * FFN * CC;
    const __bf16* W3 = w3b + (size_t)e * FFN * CC;

    __shared__ __align__(16) __bf16 sA[3][8192];   // 48 KiB: 256 rows x 32
    __shared__ __align__(16) __bf16 sB[3][4096];   // 24 KiB: 128 rows x 32

    const int tid  = threadIdx.x;
    const int lane = tid & 63, wave = tid >> 6;
    const int l15  = lane & 15, lq = lane >> 4;
    const int wm   = wave & 3;     // 4 m-quarters (64 rows each)
    const int wq   = wave >> 2;    // 2 n-halves (32 H-cols each)
    const int rsw  = (lq ^ ((l15 >> 1) & 3)) * 8;        // frag-read swizzle

    // staging swizzle (row parity built in; 16-row-aligned bases keep it exact)
    const int csw  = ((tid & 3) ^ ((tid >> 3) & 3)) * 8;    // A: row=tid>>2
    const int cswb = ((lane & 3) ^ ((lane >> 3) & 3)) * 8;  // B: row=w*16+(l>>2)

    // A: gathered token rows mt + {0,128} + tid>>2 (clamped)
    int pr0 = mt + (tid >> 2);        if (pr0 > cntE - 1) pr0 = cntE - 1;
    int pr1 = mt + 128 + (tid >> 2);  if (pr1 > cntE - 1) pr1 = cntE - 1;
    const __bf16* gA0 = X + (size_t)idxl[e * TT + pr0] * CC + csw;
    const __bf16* gA1 = X + (size_t)idxl[e * TT + pr1] * CC + csw;
    // B: wave w stages B-LDS rows [w*16, w*16+16) from (w odd ? W3 : W1),
    // cols n0 + (w>>1)*16 + (lane>>2)
    const __bf16* WB  = (wave & 1) ? W3 : W1;
    const __bf16* gB0 = WB + (size_t)(n0 + (wave >> 1) * 16 + (lane >> 2)) * CC + cswb;

    const int stA  = wave * 512;                  // stage LDS elem base
    const int aoff = (wm * 64 + l15) * 32 + rsw;  // + mf*512
    const int boff = (wq * 64 + l15) * 32 + rsw;  // + nf*512

    f32x4 acc[4][4] = {};

    // prologue: stage tiles 0,1 (slots 0,1)
    gl_lds16(gA0,      &sA[0][stA]); gl_lds16(gA1,      &sA[0][stA + 4096]);
    gl_lds16(gB0,      &sB[0][stA]);
    gl_lds16(gA0 + 32, &sA[1][stA]); gl_lds16(gA1 + 32, &sA[1][stA + 4096]);
    gl_lds16(gB0 + 32, &sB[1][stA]);
    WAITV(3);
    barrier_raw();

    int kb = 64;
    for (int it = 0; it < 10; ++it) {
        GT_TILE(0, 2, kb, 1, WAITV(3)); kb += 32;
        GT_TILE(1, 0, kb, 1, WAITV(3)); kb += 32;
        GT_TILE(2, 1, kb, 1, WAITV(3)); kb += 32;
    }
    GT_TILE(0, 0, 0, 0, WAITV(0));   // tile 30: drain tile 31's loads
    GT_TILE(1, 0, 0, 0, (void)0);    // tile 31

    // epilogue: nf0=W1 / nf1=W3 @ col, nf2=W1 / nf3=W3 @ col+16
#pragma unroll
    for (int mf = 0; mf < 4; ++mf) {
        const int gr  = goff + mt + wm * 64 + mf * 16 + lq * 4;
        const int col = n0 + wq * 32 + l15;
#pragma unroll
        for (int r = 0; r < 4; ++r) {
            const float a0 = acc[mf][0][r], c0 = acc[mf][1][r];
            const float a1 = acc[mf][2][r], c1 = acc[mf][3][r];
            H[(size_t)(gr + r) * FFN + col]      = (__bf16)(gelu_fast(a0) * c0);
            H[(size_t)(gr + r) * FFN + col + 16] = (__bf16)(gelu_fast(a1) * c1);
        }
    }
}

// ---------------------------------------------------------------------------
// GEMM2: Z = H @ W2^T, bf16, grouped. BM=256, BN=128, BK=32, same ring.
// grid (CC/128, MAXTILES).
// ---------------------------------------------------------------------------
__global__ __launch_bounds__(512, 4)
void k_gemm2(const __bf16* __restrict__ H, const __bf16* __restrict__ w2b,
             const int* __restrict__ cnt, __bf16* __restrict__ Z) {
    const int lid = blockIdx.y * 8 + blockIdx.x;
    const int wg  = xcd_swz(lid, 8 * MAXTILES);
    const int n0  = (wg & 7) * 128;
    int ty = wg >> 3;
    int e = -1, mt = 0, goff = 0, acc_rows = 0;
#pragma unroll
    for (int ee = 0; ee < EE; ++ee) {
        const int me = (cnt[ee] + 255) >> 8;
        if (ty >= 0 && ty < me) { e = ee; mt = ty << 8; goff = acc_rows; }
        ty -= me;
        acc_rows += me << 8;
    }
    if (e < 0) return;
    const __bf16* W2 = w2b + (size_t)e * CC * FFN;
    const __bf16* Ar = H + (size_t)(goff + mt) * FFN;

    __shared__ __align__(16) __bf16 sA[3][8192];   // 48 KiB
    __shared__ __align__(16) __bf16 sB[3][4096];   // 24 KiB

    const int tid  = threadIdx.x;
    const int lane = tid & 63, wave = tid >> 6;
    const int l15  = lane & 15, lq = lane >> 4;
    const int wm   = wave & 3;
    const int wq   = wave >> 2;
    const int rsw  = (lq ^ ((l15 >> 1) & 3)) * 8;
    const int csw  = ((tid & 3) ^ ((tid >> 3) & 3)) * 8;
    const int cswb = ((lane & 3) ^ ((lane >> 3) & 3)) * 8;

    const __bf16* gA0 = Ar + (size_t)(tid >> 2) * FFN + csw;
    const __bf16* gA1 = Ar + (size_t)(128 + (tid >> 2)) * FFN + csw;
    // B: wave w stages B-LDS rows [w*16, w*16+16) from W2 rows n0+w*16+(l>>2)
    const __bf16* gB0 = W2 + (size_t)(n0 + wave * 16 + (lane >> 2)) * FFN + cswb;

    const int stA  = wave * 512;
    const int aoff = (wm * 64 + l15) * 32 + rsw;
    const int boff = (wq * 64 + l15) * 32 + rsw;

    f32x4 acc[4][4] = {};

    gl_lds16(gA0,      &sA[0][stA]); gl_lds16(gA1,      &sA[0][stA + 4096]);
    gl_lds16(gB0,      &sB[0][stA]);
    gl_lds16(gA0 + 32, &sA[1][stA]); gl_lds16(gA1 + 32, &sA[1][stA + 4096]);
    gl_lds16(gB0 + 32, &sB[1][stA]);
    WAITV(3);
    barrier_raw();

    int kb = 64;
    for (int it = 0; it < 10; ++it) {
        GT_TILE(0, 2, kb, 1, WAITV(3)); kb += 32;
        GT_TILE(1, 0, kb, 1, WAITV(3)); kb += 32;
        GT_TILE(2, 1, kb, 1, WAITV(3)); kb += 32;
    }
    GT_TILE(0, 0, 0, 0, WAITV(0));   // tile 30
    GT_TILE(1, 0, 0, 0, (void)0);    // tile 31

#pragma unroll
    for (int mf = 0; mf < 4; ++mf) {
        const int gr = goff + mt + wm * 64 + mf * 16 + lq * 4;
#pragma unroll
        for (int nf = 0; nf < 4; ++nf) {
            const int col = n0 + wq * 64 + nf * 16 + l15;
#pragma unroll
            for (int r = 0; r < 4; ++r)
                Z[(size_t)(gr + r) * CC + col] = (__bf16)acc[mf][nf][r];
        }
    }
}

// ---------------------------------------------------------------------------
// k_combine: out[t,c] = w1*Z[r1,c] + w2*Z[r2,c], transposed to (B,C,H,W).
// Expert row offsets computed inline from cnt.
// ---------------------------------------------------------------------------
__global__ __launch_bounds__(256) void k_combine(const __bf16* __restrict__ Z,
                                                 const int* __restrict__ cnt,
                                                 const int* __restrict__ tokE,
                                                 const int* __restrict__ tokP,
                                                 const float* __restrict__ tokW,
                                                 float* __restrict__ out) {
    __shared__ float tile[32][33];
    __shared__ int s_pre[EE];
    const int tid = threadIdx.x;
    if (tid < EE) {
        int a = 0;
        for (int ee = 0; ee < tid; ++ee) a += ((cnt[ee] + 255) >> 8) << 8;
        s_pre[tid] = a;
    }
    __syncthreads();

    const int t0 = blockIdx.x * 32;
    const int c0 = blockIdx.y * 32;
    const int tx = tid & 31;
    const int ty = tid >> 5;

#pragma unroll
    for (int i = 0; i < 4; ++i) {
        const int tl = ty + 8 * i;
        const int t  = t0 + tl;
        const int ee = tokE[t];
        const int e1 = ee & 0xff, e2 = ee >> 8;
        const int r1 = s_pre[e1] + tokP[2 * t];
        const int r2 = s_pre[e2] + tokP[2 * t + 1];
        const float v = tokW[2 * t]     * (float)Z[(size_t)r1 * CC + c0 + tx]
                      + tokW[2 * t + 1] * (float)Z[(size_t)r2 * CC + c0 + tx];
        tile[tl][tx] = v;
    }
    __syncthreads();

    const int b   = t0 >> 12;
    const int hw0 = t0 & 4095;
#pragma unroll
    for (int i = 0; i < 4; ++i) {
        const int cl = ty + 8 * i;
        out[(size_t)b * CC * HWH + (size_t)(c0 + cl) * HWH + hw0 + tx] = tile[tx][cl];
    }
}

// ---------------------------------------------------------------------------
extern "C" void kernel_launch(void* const* d_in, const int* in_sizes, int n_in,
                              void* d_out, int out_size, void* d_ws, size_t ws_size,
                              hipStream_t stream) {
    const float* hs     = (const float*)d_in[0];
    const float* gate_w = (const float*)d_in[1];
    const float* w1     = (const float*)d_in[2];
    const float* w2     = (const float*)d_in[3];
    const float* w3     = (const float*)d_in[4];
    float* out = (float*)d_out;

    const size_t WSZ = (size_t)EE * FFN * CC * 2;   // 16 MB per bf16 weight
    char* ws = (char*)d_ws;
    __bf16* w2b  = (__bf16*)ws;                     // [0, 16M)   live: gemm2
    __bf16* w1b  = (__bf16*)(ws + WSZ);             // [16M,32M)  live: gemm1
    __bf16* w3b  = (__bf16*)(ws + 2 * WSZ);         // [32M,48M)  live: gemm1
    __bf16* X    = (__bf16*)(ws + 3 * WSZ);         // [48M,64M)  live: gemm1
    __bf16* Zbuf = (__bf16*)(ws + WSZ);             // overlays w1b,w3b,X-head
    __bf16* Hbuf = (__bf16*)(ws + 4 * WSZ);         // ~35.5 MiB
    float*  logP = (float*)Hbuf;                    // 4 MB, dead before gemm1
    char* p = ws + 4 * WSZ + (size_t)HCAP * FFN * 2;
    int*   idxl  = (int*)p;           p += (size_t)EE * TT * 4;
    int*   tokE  = (int*)p;           p += (size_t)TT * 4;
    int*   tokP  = (int*)p;           p += (size_t)2 * TT * 4;
    float* tokW  = (float*)p;         p += (size_t)2 * TT * 4;
    int*   cnt   = (int*)p;           p += 256;

    hipMemsetAsync(cnt, 0, EE * sizeof(int), stream);

    k_prep<<<CVB + XPB + RTB, 256, 0, stream>>>(
        hs, gate_w, w1, w2, w3, w1b, w2b, w3b, X, logP);
    k_top2<<<TT / 256, 256, 0, stream>>>(logP, cnt, idxl, tokE, tokP, tokW);

    k_gemm1<<<dim3(FFN / 64, MAXTILES), 512, 0, stream>>>(
        X, w1b, w3b, cnt, idxl, Hbuf);
    k_gemm2<<<dim3(CC / 128, MAXTILES), 512, 0, stream>>>(
        Hbuf, w2b, cnt, Zbuf);
    k_combine<<<dim3(TT / 32, CC / 32), 256, 0, stream>>>(
        Zbuf, cnt, tokE, tokP, tokW, out);
}